// Round 2
// baseline (808.999 us; speedup 1.0000x reference)
//
#include <hip/hip_runtime.h>
#include <math.h>

// ---------------------------------------------------------------------------
// OptimizedProtoHyperFormer — fp32, round 2: latency/occupancy fixes.
// B=32, IB=103, H=W=256, P=16, RB=8, DIM=192, DEPTH=3, KS=KP=24, TOPK=2,
// NC=9, FFH=384. Tokens: 16x16=256 per batch, NT=8192.
// ---------------------------------------------------------------------------

__device__ __forceinline__ float wsum64(float v) {
#pragma unroll
  for (int o = 32; o > 0; o >>= 1) v += __shfl_xor(v, o, 64);
  return v;
}
__device__ __forceinline__ float wmax64(float v) {
#pragma unroll
  for (int o = 32; o > 0; o >>= 1) v = fmaxf(v, __shfl_xor(v, o, 64));
  return v;
}
__device__ __forceinline__ float sum16(float v) {
#pragma unroll
  for (int o = 8; o > 0; o >>= 1) v += __shfl_xor(v, o, 64);
  return v;
}
__device__ __forceinline__ float gelu_f(float x) {
  return 0.5f * x * (1.0f + erff(x * 0.7071067811865476f));
}

// ---------------------------------------------------------------------------
// K1: fused band-reduction (103->8) + depthwise 16x16 patch conv.
// 512 blocks (batch x patch-row), 512 threads. One-channel software prefetch.
// ---------------------------------------------------------------------------
__global__ __launch_bounds__(512) void k1_band_dw(
    const float* __restrict__ x, const float* __restrict__ band_w,
    const float* __restrict__ band_b, const float* __restrict__ dw_w,
    float* __restrict__ dw_out) {
  const int blk = blockIdx.x;
  const int b = blk >> 4, ip = blk & 15;
  const int t = threadIdx.x;
  const int col4 = t & 63;
  const int j = col4 >> 2;
  const int qb = (col4 & 3) << 2;
  const int p0 = t >> 6;

  float acc[8][8];
#pragma unroll
  for (int e = 0; e < 8; ++e)
#pragma unroll
    for (int c = 0; c < 8; ++c) acc[e][c] = 0.f;

  const float4* xp = (const float4*)x + (size_t)b * (103 * 16384) + (size_t)ip * 1024;

  auto body = [&](const float4 v0, const float4 v1, const int ch) {
#pragma unroll
    for (int c = 0; c < 8; ++c) {
      const float bw = band_w[c * 103 + ch];
      acc[0][c] = fmaf(v0.x, bw, acc[0][c]);
      acc[1][c] = fmaf(v0.y, bw, acc[1][c]);
      acc[2][c] = fmaf(v0.z, bw, acc[2][c]);
      acc[3][c] = fmaf(v0.w, bw, acc[3][c]);
      acc[4][c] = fmaf(v1.x, bw, acc[4][c]);
      acc[5][c] = fmaf(v1.y, bw, acc[5][c]);
      acc[6][c] = fmaf(v1.z, bw, acc[6][c]);
      acc[7][c] = fmaf(v1.w, bw, acc[7][c]);
    }
  };

  float4 v0 = xp[t];
  float4 v1 = xp[t + 512];
#pragma unroll 1
  for (int ch = 0; ch < 102; ++ch) {
    const float4 n0 = xp[t + 16384];
    const float4 n1 = xp[t + 512 + 16384];
    body(v0, v1, ch);
    v0 = n0;
    v1 = n1;
    xp += 16384;
  }
  body(v0, v1, 102);

  float dwt[8];
#pragma unroll
  for (int c = 0; c < 8; ++c) dwt[c] = 0.f;
#pragma unroll
  for (int e = 0; e < 8; ++e) {
    const int pp = p0 + ((e >> 2) << 3);
    const int qq = qb + (e & 3);
#pragma unroll
    for (int c = 0; c < 8; ++c)
      dwt[c] = fmaf(dw_w[c * 256 + pp * 16 + qq], acc[e][c] + band_b[c], dwt[c]);
  }
#pragma unroll
  for (int c = 0; c < 8; ++c) {
    dwt[c] += __shfl_xor(dwt[c], 1, 64);
    dwt[c] += __shfl_xor(dwt[c], 2, 64);
  }
  __shared__ float part[8][16][8];
  if ((t & 3) == 0) {
#pragma unroll
    for (int c = 0; c < 8; ++c) part[t >> 6][j][c] = dwt[c];
  }
  __syncthreads();
  if (t < 128) {
    const int jj = t >> 3, c = t & 7;
    float s = 0.f;
#pragma unroll
    for (int w = 0; w < 8; ++w) s += part[w][jj][c];
    dw_out[(((size_t)b * 16 + ip) * 16 + jj) * 8 + c] = s;
  }
}

// ---------------------------------------------------------------------------
// K2: token pipeline (pw+LN -> router -> top2 -> proto mix -> keys).
// 16 tokens/block, 256 threads, 512 blocks.
// ---------------------------------------------------------------------------
__global__ __launch_bounds__(256) void k2_token(
    const float* __restrict__ dw, const float* __restrict__ pw_w,
    const float* __restrict__ pe_ln_w, const float* __restrict__ pe_ln_b,
    const float* __restrict__ spec_proto, const float* __restrict__ spat_proto,
    const float* __restrict__ r1_w, const float* __restrict__ r1_b,
    const float* __restrict__ r2_w, const float* __restrict__ r2_b,
    const float* __restrict__ key_w, const float* __restrict__ pos_bias,
    float* __restrict__ xb_out, float* __restrict__ keys_out) {
  const int t = threadIdx.x;
  const int tx = t & 63, ty = t >> 6;
  const int tok0 = blockIdx.x * 16;

  __shared__ float dw8s[16][8];
  __shared__ float xnT[192][20];
  __shared__ float hT[128][20];
  __shared__ float rlS[16][48];
  __shared__ float topwS[16][4];
  __shared__ int   topiS[16][4];
  __shared__ float mixT[200][20];

  if (t < 128) {
    const int tt = t >> 3, c = t & 7;
    dw8s[tt][c] = dw[((size_t)tok0 + tt) * 8 + c];
  }
  __syncthreads();

  // ---- phase 1: pw + LN ----
  {
    const int tt = t >> 4, lg = t & 15;
    float pre[12];
    float sm = 0.f;
#pragma unroll
    for (int m = 0; m < 12; ++m) {
      const int d = lg + 16 * m;
      const float4 pa = *(const float4*)&pw_w[d * 8];
      const float4 pb = *(const float4*)&pw_w[d * 8 + 4];
      float p = pa.x * dw8s[tt][0] + pa.y * dw8s[tt][1] + pa.z * dw8s[tt][2] +
                pa.w * dw8s[tt][3] + pb.x * dw8s[tt][4] + pb.y * dw8s[tt][5] +
                pb.z * dw8s[tt][6] + pb.w * dw8s[tt][7];
      pre[m] = p;
      sm += p;
    }
    sm = sum16(sm);
    const float mean = sm * (1.f / 192.f);
    float vv = 0.f;
#pragma unroll
    for (int m = 0; m < 12; ++m) {
      const float d0 = pre[m] - mean;
      vv = fmaf(d0, d0, vv);
    }
    vv = sum16(vv);
    const float inv = rsqrtf(vv * (1.f / 192.f) + 1e-5f);
#pragma unroll
    for (int m = 0; m < 12; ++m) {
      const int d = lg + 16 * m;
      const float xv = (pre[m] - mean) * inv * pe_ln_w[d] + pe_ln_b[d];
      xnT[d][tt] = xv;
      xb_out[((size_t)tok0 + tt) * 192 + d] = xv;
    }
  }
  __syncthreads();

  // ---- phase 2: r1 (192->128) + gelu ----
  {
    float a1[4][2];
#pragma unroll
    for (int i = 0; i < 4; ++i) {
      a1[i][0] = r1_b[tx];
      a1[i][1] = r1_b[tx + 64];
    }
#pragma unroll 4
    for (int k = 0; k < 192; ++k) {
      const float4 a = *(const float4*)&xnT[k][ty << 2];
      const float av[4] = {a.x, a.y, a.z, a.w};
#pragma unroll
      for (int m = 0; m < 2; ++m) {
        const float w = r1_w[k * 128 + tx + 64 * m];
#pragma unroll
        for (int i = 0; i < 4; ++i) a1[i][m] = fmaf(av[i], w, a1[i][m]);
      }
    }
#pragma unroll
    for (int i = 0; i < 4; ++i) {
      hT[tx][(ty << 2) + i] = gelu_f(a1[i][0]);
      hT[tx + 64][(ty << 2) + i] = gelu_f(a1[i][1]);
    }
  }
  __syncthreads();

  // ---- phase 3: r2 (128->48) ----
  if (tx < 48) {
    float a2[4];
#pragma unroll
    for (int i = 0; i < 4; ++i) a2[i] = r2_b[tx];
#pragma unroll 4
    for (int k = 0; k < 128; ++k) {
      const float4 a = *(const float4*)&hT[k][ty << 2];
      const float av[4] = {a.x, a.y, a.z, a.w};
      const float w = r2_w[k * 48 + tx];
#pragma unroll
      for (int i = 0; i < 4; ++i) a2[i] = fmaf(av[i], w, a2[i]);
    }
#pragma unroll
    for (int i = 0; i < 4; ++i) rlS[(ty << 2) + i][tx] = a2[i];
  }
  __syncthreads();

  // ---- phase 4: top-2 + tau softmax ----
  if (t < 32) {
    const int tt = t >> 1, half = t & 1;
    const float* base = &rlS[tt][half * 24];
    float v0 = -1e30f, v1 = -1e30f;
    int i0 = 0, i1 = 0;
    for (int k = 0; k < 24; ++k) {
      const float vv = base[k];
      if (vv > v0) { v1 = v0; i1 = i0; v0 = vv; i0 = k; }
      else if (vv > v1) { v1 = vv; i1 = k; }
    }
    const float tau = (float)(0.07 + 1e-8);
    const float e1 = expf((v1 - v0) / tau);
    const float inv = 1.f / (1.f + e1);
    topwS[tt][half * 2] = inv;
    topwS[tt][half * 2 + 1] = e1 * inv;
    topiS[tt][half * 2] = i0;
    topiS[tt][half * 2 + 1] = i1;
  }
  __syncthreads();

  // ---- phase 5: mixed prototypes mixT[200][16] ----
#pragma unroll
  for (int r = 0; r < 13; ++r) {
    const int f = t + 256 * r;
    if (f < 3200) {
      const int c = f >> 4, tt = f & 15;
      float val;
      if (c < 8) {
        val = topwS[tt][0] * spec_proto[topiS[tt][0] * 8 + c] +
              topwS[tt][1] * spec_proto[topiS[tt][1] * 8 + c];
      } else {
        const int cc = c - 8;
        val = topwS[tt][2] * spat_proto[topiS[tt][2] * 192 + cc] +
              topwS[tt][3] * spat_proto[topiS[tt][3] * 192 + cc];
      }
      mixT[c][tt] = val;
    }
  }
  __syncthreads();

  // ---- phase 6: keys (200->192) + pos_bias ----
  {
    float ak[4][3];
#pragma unroll
    for (int i = 0; i < 4; ++i)
#pragma unroll
      for (int m = 0; m < 3; ++m) ak[i][m] = pos_bias[tx + 64 * m];
#pragma unroll 4
    for (int k = 0; k < 200; ++k) {
      const float4 a = *(const float4*)&mixT[k][ty << 2];
      const float av[4] = {a.x, a.y, a.z, a.w};
#pragma unroll
      for (int m = 0; m < 3; ++m) {
        const float w = key_w[k * 192 + tx + 64 * m];
#pragma unroll
        for (int i = 0; i < 4; ++i) ak[i][m] = fmaf(av[i], w, ak[i][m]);
      }
    }
#pragma unroll
    for (int i = 0; i < 4; ++i) {
      const size_t row = ((size_t)tok0 + (ty << 2) + i) * 192;
#pragma unroll
      for (int m = 0; m < 3; ++m) keys_out[row + tx + 64 * m] = ak[i][m];
    }
  }
}

// ---------------------------------------------------------------------------
// K3a: xn = LN(xb); q -> softmax -> qs; v. 16 tokens/block, 512 blocks.
// ---------------------------------------------------------------------------
__global__ __launch_bounds__(256) void k3a_qv(
    const float* __restrict__ xb, const float* __restrict__ lnw,
    const float* __restrict__ lnb, const float* __restrict__ qw,
    const float* __restrict__ vw, float* __restrict__ qs_out,
    float* __restrict__ v_out, int depth) {
  const int t = threadIdx.x;
  const int tx = t & 63, ty = t >> 6;
  const int tok0 = blockIdx.x * 16;
  __shared__ float xnT[192][20];
  {
    const int tt = t >> 4, lg = t & 15;
    const float* xrow = xb + ((size_t)tok0 + tt) * 192;
    float vals[12];
    float sm = 0.f;
#pragma unroll
    for (int m = 0; m < 12; ++m) {
      vals[m] = xrow[lg + 16 * m];
      sm += vals[m];
    }
    sm = sum16(sm);
    const float mean = sm * (1.f / 192.f);
    float vv = 0.f;
#pragma unroll
    for (int m = 0; m < 12; ++m) {
      const float d0 = vals[m] - mean;
      vv = fmaf(d0, d0, vv);
    }
    vv = sum16(vv);
    const float inv = rsqrtf(vv * (1.f / 192.f) + 1e-5f);
    const float* lw = lnw + depth * 192;
    const float* lb = lnb + depth * 192;
#pragma unroll
    for (int m = 0; m < 12; ++m) {
      const int d = lg + 16 * m;
      xnT[d][tt] = (vals[m] - mean) * inv * lw[d] + lb[d];
    }
  }
  __syncthreads();

  float accq[4][3], accv[4][3];
#pragma unroll
  for (int i = 0; i < 4; ++i)
#pragma unroll
    for (int m = 0; m < 3; ++m) { accq[i][m] = 0.f; accv[i][m] = 0.f; }

  const float* qp = qw + (size_t)depth * 192 * 192;
  const float* vp = vw + (size_t)depth * 192 * 192;
#pragma unroll 4
  for (int k = 0; k < 192; ++k) {
    const float4 a = *(const float4*)&xnT[k][ty << 2];
    const float av[4] = {a.x, a.y, a.z, a.w};
#pragma unroll
    for (int m = 0; m < 3; ++m) {
      const float wq = qp[k * 192 + tx + 64 * m];
      const float wv = vp[k * 192 + tx + 64 * m];
#pragma unroll
      for (int i = 0; i < 4; ++i) {
        accq[i][m] = fmaf(av[i], wq, accq[i][m]);
        accv[i][m] = fmaf(av[i], wv, accv[i][m]);
      }
    }
  }
#pragma unroll
  for (int i = 0; i < 4; ++i) {
    const size_t row = ((size_t)tok0 + (ty << 2) + i) * 192;
#pragma unroll
    for (int m = 0; m < 3; ++m) v_out[row + tx + 64 * m] = accv[i][m];
    float mx = fmaxf(accq[i][0], fmaxf(accq[i][1], accq[i][2]));
    mx = wmax64(mx);
    const float e0 = expf(accq[i][0] - mx);
    const float e1 = expf(accq[i][1] - mx);
    const float e2 = expf(accq[i][2] - mx);
    const float ssum = wsum64(e0 + e1 + e2);
    const float inv = 1.f / ssum;
    qs_out[row + tx] = e0 * inv;
    qs_out[row + tx + 64] = e1 * inv;
    qs_out[row + tx + 128] = e2 * inv;
  }
}

// ---------------------------------------------------------------------------
// K3b: partial KV. Grid: 32 b x 8 ct x 4 token-quarters = 1024 blocks.
// kvp[ts][b][c][d]; reduced by k3b_red.
// ---------------------------------------------------------------------------
__global__ __launch_bounds__(256) void k3b_kv(
    const float* __restrict__ keys, const float* __restrict__ v,
    float* __restrict__ kvp) {
  const int blk = blockIdx.x;
  const int ts = blk & 3;
  const int ct = (blk >> 2) & 7;
  const int b = blk >> 5;
  const int c0 = ct * 24;
  const int t = threadIdx.x;
  const int ci = t >> 6;
  const int di = t & 63;
  __shared__ float ks[16][24];
  __shared__ float vs[16][192];
  float acc[6][3];
#pragma unroll
  for (int i = 0; i < 6; ++i)
#pragma unroll
    for (int u = 0; u < 3; ++u) acc[i][u] = 0.f;

  for (int s = 0; s < 4; ++s) {
    const size_t tokbase = (size_t)b * 256 + ts * 64 + s * 16;
    if (t < 96) {
      const int nn = t / 6, u = t % 6;
      *(float4*)&ks[nn][u * 4] =
          *(const float4*)&keys[(tokbase + nn) * 192 + c0 + u * 4];
    }
    {
      const float4* vp = (const float4*)(v + tokbase * 192);
      float4* vsp = (float4*)vs;
#pragma unroll
      for (int r = 0; r < 3; ++r) vsp[t + 256 * r] = vp[t + 256 * r];
    }
    __syncthreads();
#pragma unroll 8
    for (int n = 0; n < 16; ++n) {
      float kc[6];
      *(float2*)&kc[0] = *(const float2*)&ks[n][ci * 6];
      *(float2*)&kc[2] = *(const float2*)&ks[n][ci * 6 + 2];
      *(float2*)&kc[4] = *(const float2*)&ks[n][ci * 6 + 4];
      const float vd0 = vs[n][di];
      const float vd1 = vs[n][di + 64];
      const float vd2 = vs[n][di + 128];
#pragma unroll
      for (int i = 0; i < 6; ++i) {
        acc[i][0] = fmaf(kc[i], vd0, acc[i][0]);
        acc[i][1] = fmaf(kc[i], vd1, acc[i][1]);
        acc[i][2] = fmaf(kc[i], vd2, acc[i][2]);
      }
    }
    __syncthreads();
  }
  float* outp = kvp + (size_t)ts * 1179648 + (size_t)b * 36864;
#pragma unroll
  for (int i = 0; i < 6; ++i)
#pragma unroll
    for (int u = 0; u < 3; ++u)
      outp[(c0 + ci * 6 + i) * 192 + di + 64 * u] = acc[i][u];
}

__global__ __launch_bounds__(256) void k3b_red(
    const float* __restrict__ kvp, float* __restrict__ kv) {
  const int i = blockIdx.x * 256 + threadIdx.x;  // 1,179,648 total
  kv[i] = kvp[i] + kvp[i + 1179648] + kvp[i + 2 * 1179648] + kvp[i + 3 * 1179648];
}

// ---------------------------------------------------------------------------
// K3c: out = qs@KV; residual; LN; FFN; residual. 16 tokens/block, 512 blocks.
// ---------------------------------------------------------------------------
__global__ __launch_bounds__(256) void k3c_ff(
    float* __restrict__ xb, const float* __restrict__ qs,
    const float* __restrict__ kv, const float* __restrict__ lnw,
    const float* __restrict__ lnb, const float* __restrict__ f1w,
    const float* __restrict__ f1b, const float* __restrict__ f2w,
    const float* __restrict__ f2b, const float* __restrict__ g1,
    const float* __restrict__ g2, int depth) {
  const int t = threadIdx.x;
  const int tx = t & 63, ty = t >> 6;
  const int tok0 = blockIdx.x * 16;
  const int b = blockIdx.x >> 4;
  __shared__ float aT[192][20];
  __shared__ float fT[384][20];

#pragma unroll
  for (int r = 0; r < 12; ++r) {
    const int f = t + 256 * r;
    const int d = f % 192, tt = f / 192;
    aT[d][tt] = qs[((size_t)tok0 + tt) * 192 + d];
  }
  __syncthreads();

  float o1[4][3];
#pragma unroll
  for (int i = 0; i < 4; ++i)
#pragma unroll
    for (int m = 0; m < 3; ++m) o1[i][m] = 0.f;
  const float* kvb = kv + (size_t)b * 36864;
#pragma unroll 4
  for (int k = 0; k < 192; ++k) {
    const float4 a = *(const float4*)&aT[k][ty << 2];
    const float av[4] = {a.x, a.y, a.z, a.w};
#pragma unroll
    for (int m = 0; m < 3; ++m) {
      const float w = kvb[k * 192 + tx + 64 * m];
#pragma unroll
      for (int i = 0; i < 4; ++i) o1[i][m] = fmaf(av[i], w, o1[i][m]);
    }
  }

  float xbn[4][3];
  const float* g1p = g1 + depth * 192;
#pragma unroll
  for (int i = 0; i < 4; ++i) {
    const size_t row = ((size_t)tok0 + (ty << 2) + i) * 192;
#pragma unroll
    for (int m = 0; m < 3; ++m)
      xbn[i][m] = xb[row + tx + 64 * m] + o1[i][m] * g1p[tx + 64 * m];
  }
  __syncthreads();

  const float* lw = lnw + depth * 192;
  const float* lb = lnb + depth * 192;
#pragma unroll
  for (int i = 0; i < 4; ++i) {
    float sm = xbn[i][0] + xbn[i][1] + xbn[i][2];
    sm = wsum64(sm);
    const float mean = sm * (1.f / 192.f);
    float vv = 0.f;
#pragma unroll
    for (int m = 0; m < 3; ++m) {
      const float d0 = xbn[i][m] - mean;
      vv = fmaf(d0, d0, vv);
    }
    vv = wsum64(vv);
    const float inv = rsqrtf(vv * (1.f / 192.f) + 1e-5f);
#pragma unroll
    for (int m = 0; m < 3; ++m) {
      const int col = tx + 64 * m;
      aT[col][(ty << 2) + i] = (xbn[i][m] - mean) * inv * lw[col] + lb[col];
    }
  }
  __syncthreads();

  float h[4][6];
#pragma unroll
  for (int i = 0; i < 4; ++i)
#pragma unroll
    for (int m = 0; m < 6; ++m) h[i][m] = 0.f;
  const float* f1p = f1w + (size_t)depth * 192 * 384;
#pragma unroll 4
  for (int k = 0; k < 192; ++k) {
    const float4 a = *(const float4*)&aT[k][ty << 2];
    const float av[4] = {a.x, a.y, a.z, a.w};
#pragma unroll
    for (int m = 0; m < 6; ++m) {
      const float w = f1p[k * 384 + tx + 64 * m];
#pragma unroll
      for (int i = 0; i < 4; ++i) h[i][m] = fmaf(av[i], w, h[i][m]);
    }
  }
  const float* b1p = f1b + depth * 384;
#pragma unroll
  for (int i = 0; i < 4; ++i)
#pragma unroll
    for (int m = 0; m < 6; ++m) {
      const int col = tx + 64 * m;
      fT[col][(ty << 2) + i] = gelu_f(h[i][m] + b1p[col]);
    }
  __syncthreads();

  float o2[4][3];
#pragma unroll
  for (int i = 0; i < 4; ++i)
#pragma unroll
    for (int m = 0; m < 3; ++m) o2[i][m] = 0.f;
  const float* f2p = f2w + (size_t)depth * 384 * 192;
#pragma unroll 4
  for (int k = 0; k < 384; ++k) {
    const float4 a = *(const float4*)&fT[k][ty << 2];
    const float av[4] = {a.x, a.y, a.z, a.w};
#pragma unroll
    for (int m = 0; m < 3; ++m) {
      const float w = f2p[k * 192 + tx + 64 * m];
#pragma unroll
      for (int i = 0; i < 4; ++i) o2[i][m] = fmaf(av[i], w, o2[i][m]);
    }
  }
  const float* b2p = f2b + depth * 192;
  const float* g2p = g2 + depth * 192;
#pragma unroll
  for (int i = 0; i < 4; ++i) {
    const size_t row = ((size_t)tok0 + (ty << 2) + i) * 192;
#pragma unroll
    for (int m = 0; m < 3; ++m) {
      const int col = tx + 64 * m;
      xb[row + col] = xbn[i][m] + (o2[i][m] + b2p[col]) * g2p[col];
    }
  }
}

// ---------------------------------------------------------------------------
// K4: feat = LN(mean_n xb); out = feat @ head_w + head_b.
// ---------------------------------------------------------------------------
__global__ __launch_bounds__(192) void k4_head(
    const float* __restrict__ xb, const float* __restrict__ flnw,
    const float* __restrict__ flnb, const float* __restrict__ hw,
    const float* __restrict__ hb, float* __restrict__ out) {
  const int b = blockIdx.x, t = threadIdx.x;
  const int w = t >> 6, lane = t & 63;
  float s = 0.f;
  const float* base = xb + (size_t)b * 256 * 192 + t;
#pragma unroll 4
  for (int n = 0; n < 256; ++n) s += base[n * 192];
  const float feat_pre = s * (1.f / 256.f);
  __shared__ float red[3];
  __shared__ float feat[192];
  float sm = wsum64(feat_pre);
  if (lane == 0) red[w] = sm;
  __syncthreads();
  const float mean = (red[0] + red[1] + red[2]) * (1.f / 192.f);
  __syncthreads();
  const float dd = feat_pre - mean;
  sm = wsum64(dd * dd);
  if (lane == 0) red[w] = sm;
  __syncthreads();
  const float var = (red[0] + red[1] + red[2]) * (1.f / 192.f);
  feat[t] = dd * rsqrtf(var + 1e-5f) * flnw[t] + flnb[t];
  __syncthreads();
  if (t < 9) {
    float a = hb[t];
    for (int d = 0; d < 192; ++d) a = fmaf(feat[d], hw[d * 9 + t], a);
    out[b * 9 + t] = a;
  }
}

// ---------------------------------------------------------------------------
extern "C" void kernel_launch(void* const* d_in, const int* in_sizes, int n_in,
                              void* d_out, int out_size, void* d_ws, size_t ws_size,
                              hipStream_t stream) {
  (void)in_sizes; (void)n_in; (void)out_size; (void)ws_size;
  const float* x          = (const float*)d_in[0];
  const float* band_w     = (const float*)d_in[1];
  const float* band_b     = (const float*)d_in[2];
  const float* dw_w       = (const float*)d_in[3];
  const float* pw_w       = (const float*)d_in[4];
  const float* pe_ln_w    = (const float*)d_in[5];
  const float* pe_ln_b    = (const float*)d_in[6];
  const float* spec_proto = (const float*)d_in[7];
  const float* spat_proto = (const float*)d_in[8];
  const float* r1_w       = (const float*)d_in[9];
  const float* r1_b       = (const float*)d_in[10];
  const float* r2_w       = (const float*)d_in[11];
  const float* r2_b       = (const float*)d_in[12];
  const float* key_w      = (const float*)d_in[13];
  const float* pos_bias   = (const float*)d_in[14];
  const float* blk_ln_w   = (const float*)d_in[15];
  const float* blk_ln_b   = (const float*)d_in[16];
  const float* blk_q_w    = (const float*)d_in[17];
  const float* blk_v_w    = (const float*)d_in[18];
  const float* blk_f1_w   = (const float*)d_in[19];
  const float* blk_f1_b   = (const float*)d_in[20];
  const float* blk_f2_w   = (const float*)d_in[21];
  const float* blk_f2_b   = (const float*)d_in[22];
  const float* blk_g1     = (const float*)d_in[23];
  const float* blk_g2     = (const float*)d_in[24];
  const float* fin_ln_w   = (const float*)d_in[25];
  const float* fin_ln_b   = (const float*)d_in[26];
  const float* head_w     = (const float*)d_in[27];
  const float* head_b     = (const float*)d_in[28];

  float* ws   = (float*)d_ws;
  float* dw   = ws;                    // 65,536
  float* xbuf = dw + 65536;            // 1,572,864
  float* keys = xbuf + 1572864;        // 1,572,864
  float* qs   = keys + 1572864;        // 1,572,864
  float* vbuf = qs + 1572864;          // 1,572,864
  float* kv   = vbuf + 1572864;        // 1,179,648
  float* kvp  = kv + 1179648;          // 4,718,592

  k1_band_dw<<<512, 512, 0, stream>>>(x, band_w, band_b, dw_w, dw);
  k2_token<<<512, 256, 0, stream>>>(dw, pw_w, pe_ln_w, pe_ln_b, spec_proto,
                                    spat_proto, r1_w, r1_b, r2_w, r2_b, key_w,
                                    pos_bias, xbuf, keys);
  for (int d = 0; d < 3; ++d) {
    k3a_qv<<<512, 256, 0, stream>>>(xbuf, blk_ln_w, blk_ln_b, blk_q_w, blk_v_w,
                                    qs, vbuf, d);
    k3b_kv<<<1024, 256, 0, stream>>>(keys, vbuf, kvp);
    k3b_red<<<4608, 256, 0, stream>>>(kvp, kv);
    k3c_ff<<<512, 256, 0, stream>>>(xbuf, qs, kv, blk_ln_w, blk_ln_b, blk_f1_w,
                                    blk_f1_b, blk_f2_w, blk_f2_b, blk_g1,
                                    blk_g2, d);
  }
  k4_head<<<32, 192, 0, stream>>>(xbuf, fin_ln_w, fin_ln_b, head_w, head_b,
                                  (float*)d_out);
}

// Round 3
// 451.402 us; speedup vs baseline: 1.7922x; 1.7922x over previous
//
#include <hip/hip_runtime.h>
#include <math.h>

// ---------------------------------------------------------------------------
// OptimizedProtoHyperFormer — round 3: bf16 MFMA for block GEMMs.
// B=32, IB=103, H=W=256, P=16, RB=8, DIM=192, DEPTH=3, FFH=384, NT=8192.
// ---------------------------------------------------------------------------

typedef __attribute__((ext_vector_type(8))) short bf16x8;
typedef __attribute__((ext_vector_type(4))) float f32x4;

__device__ __forceinline__ float wsum64(float v) {
#pragma unroll
  for (int o = 32; o > 0; o >>= 1) v += __shfl_xor(v, o, 64);
  return v;
}
__device__ __forceinline__ float sum16(float v) {
#pragma unroll
  for (int o = 8; o > 0; o >>= 1) v += __shfl_xor(v, o, 64);
  return v;
}
__device__ __forceinline__ float max16(float v) {
#pragma unroll
  for (int o = 8; o > 0; o >>= 1) v = fmaxf(v, __shfl_xor(v, o, 64));
  return v;
}
__device__ __forceinline__ float gelu_f(float x) {
  return 0.5f * x * (1.0f + erff(x * 0.7071067811865476f));
}
__device__ __forceinline__ ushort f2bf(float f) {
  union { float f; unsigned u; } v;
  v.f = f;
  unsigned r = v.u + 0x7FFFu + ((v.u >> 16) & 1u);
  return (ushort)(r >> 16);
}

// ---------------------------------------------------------------------------
// prep: convert + transpose weights to bf16: W[k][j] -> WT[j][k]
// ---------------------------------------------------------------------------
__global__ __launch_bounds__(256) void prep_w(
    const float* __restrict__ qw, const float* __restrict__ vw,
    const float* __restrict__ f1w, const float* __restrict__ f2w,
    ushort* __restrict__ qwT, ushort* __restrict__ vwT,
    ushort* __restrict__ f1T, ushort* __restrict__ f2T) {
  const int i = blockIdx.x * 256 + threadIdx.x;
  if (i < 110592) {  // qw, vw: [3][192][192]
    const int d = i / 36864, r = i % 36864;
    const int k = r / 192, c = r % 192;
    qwT[d * 36864 + c * 192 + k] = f2bf(qw[i]);
    vwT[d * 36864 + c * 192 + k] = f2bf(vw[i]);
  }
  if (i < 221184) {
    const int d = i / 73728, r = i % 73728;
    const int k = r / 384, j = r % 384;        // f1: [3][192][384] -> [3][384][192]
    f1T[d * 73728 + j * 192 + k] = f2bf(f1w[i]);
    const int k2 = r / 192, j2 = r % 192;      // f2: [3][384][192] -> [3][192][384]
    f2T[d * 73728 + j2 * 384 + k2] = f2bf(f2w[i]);
  }
}

// ---------------------------------------------------------------------------
// K1: fused band-reduction (103->8) + depthwise patch conv. Unchanged.
// ---------------------------------------------------------------------------
__global__ __launch_bounds__(512) void k1_band_dw(
    const float* __restrict__ x, const float* __restrict__ band_w,
    const float* __restrict__ band_b, const float* __restrict__ dw_w,
    float* __restrict__ dw_out) {
  const int blk = blockIdx.x;
  const int b = blk >> 4, ip = blk & 15;
  const int t = threadIdx.x;
  const int col4 = t & 63;
  const int j = col4 >> 2;
  const int qb = (col4 & 3) << 2;
  const int p0 = t >> 6;

  float acc[8][8];
#pragma unroll
  for (int e = 0; e < 8; ++e)
#pragma unroll
    for (int c = 0; c < 8; ++c) acc[e][c] = 0.f;

  const float4* xp = (const float4*)x + (size_t)b * (103 * 16384) + (size_t)ip * 1024;

  auto body = [&](const float4 v0, const float4 v1, const int ch) {
#pragma unroll
    for (int c = 0; c < 8; ++c) {
      const float bw = band_w[c * 103 + ch];
      acc[0][c] = fmaf(v0.x, bw, acc[0][c]);
      acc[1][c] = fmaf(v0.y, bw, acc[1][c]);
      acc[2][c] = fmaf(v0.z, bw, acc[2][c]);
      acc[3][c] = fmaf(v0.w, bw, acc[3][c]);
      acc[4][c] = fmaf(v1.x, bw, acc[4][c]);
      acc[5][c] = fmaf(v1.y, bw, acc[5][c]);
      acc[6][c] = fmaf(v1.z, bw, acc[6][c]);
      acc[7][c] = fmaf(v1.w, bw, acc[7][c]);
    }
  };

  float4 v0 = xp[t];
  float4 v1 = xp[t + 512];
#pragma unroll 1
  for (int ch = 0; ch < 102; ++ch) {
    const float4 n0 = xp[t + 16384];
    const float4 n1 = xp[t + 512 + 16384];
    body(v0, v1, ch);
    v0 = n0;
    v1 = n1;
    xp += 16384;
  }
  body(v0, v1, 102);

  float dwt[8];
#pragma unroll
  for (int c = 0; c < 8; ++c) dwt[c] = 0.f;
#pragma unroll
  for (int e = 0; e < 8; ++e) {
    const int pp = p0 + ((e >> 2) << 3);
    const int qq = qb + (e & 3);
#pragma unroll
    for (int c = 0; c < 8; ++c)
      dwt[c] = fmaf(dw_w[c * 256 + pp * 16 + qq], acc[e][c] + band_b[c], dwt[c]);
  }
#pragma unroll
  for (int c = 0; c < 8; ++c) {
    dwt[c] += __shfl_xor(dwt[c], 1, 64);
    dwt[c] += __shfl_xor(dwt[c], 2, 64);
  }
  __shared__ float part[8][16][8];
  if ((t & 3) == 0) {
#pragma unroll
    for (int c = 0; c < 8; ++c) part[t >> 6][j][c] = dwt[c];
  }
  __syncthreads();
  if (t < 128) {
    const int jj = t >> 3, c = t & 7;
    float s = 0.f;
#pragma unroll
    for (int w = 0; w < 8; ++w) s += part[w][jj][c];
    dw_out[(((size_t)b * 16 + ip) * 16 + jj) * 8 + c] = s;
  }
}

// ---------------------------------------------------------------------------
// K2: token pipeline, fp32 (router precision). Unchanged.
// ---------------------------------------------------------------------------
__global__ __launch_bounds__(256) void k2_token(
    const float* __restrict__ dw, const float* __restrict__ pw_w,
    const float* __restrict__ pe_ln_w, const float* __restrict__ pe_ln_b,
    const float* __restrict__ spec_proto, const float* __restrict__ spat_proto,
    const float* __restrict__ r1_w, const float* __restrict__ r1_b,
    const float* __restrict__ r2_w, const float* __restrict__ r2_b,
    const float* __restrict__ key_w, const float* __restrict__ pos_bias,
    float* __restrict__ xb_out, float* __restrict__ keys_out) {
  const int t = threadIdx.x;
  const int tx = t & 63, ty = t >> 6;
  const int tok0 = blockIdx.x * 16;

  __shared__ float dw8s[16][8];
  __shared__ float xnT[192][20];
  __shared__ float hT[128][20];
  __shared__ float rlS[16][48];
  __shared__ float topwS[16][4];
  __shared__ int   topiS[16][4];
  __shared__ float mixT[200][20];

  if (t < 128) {
    const int tt = t >> 3, c = t & 7;
    dw8s[tt][c] = dw[((size_t)tok0 + tt) * 8 + c];
  }
  __syncthreads();

  {
    const int tt = t >> 4, lg = t & 15;
    float pre[12];
    float sm = 0.f;
#pragma unroll
    for (int m = 0; m < 12; ++m) {
      const int d = lg + 16 * m;
      const float4 pa = *(const float4*)&pw_w[d * 8];
      const float4 pb = *(const float4*)&pw_w[d * 8 + 4];
      float p = pa.x * dw8s[tt][0] + pa.y * dw8s[tt][1] + pa.z * dw8s[tt][2] +
                pa.w * dw8s[tt][3] + pb.x * dw8s[tt][4] + pb.y * dw8s[tt][5] +
                pb.z * dw8s[tt][6] + pb.w * dw8s[tt][7];
      pre[m] = p;
      sm += p;
    }
    sm = sum16(sm);
    const float mean = sm * (1.f / 192.f);
    float vv = 0.f;
#pragma unroll
    for (int m = 0; m < 12; ++m) {
      const float d0 = pre[m] - mean;
      vv = fmaf(d0, d0, vv);
    }
    vv = sum16(vv);
    const float inv = rsqrtf(vv * (1.f / 192.f) + 1e-5f);
#pragma unroll
    for (int m = 0; m < 12; ++m) {
      const int d = lg + 16 * m;
      const float xv = (pre[m] - mean) * inv * pe_ln_w[d] + pe_ln_b[d];
      xnT[d][tt] = xv;
      xb_out[((size_t)tok0 + tt) * 192 + d] = xv;
    }
  }
  __syncthreads();

  {
    float a1[4][2];
#pragma unroll
    for (int i = 0; i < 4; ++i) {
      a1[i][0] = r1_b[tx];
      a1[i][1] = r1_b[tx + 64];
    }
#pragma unroll 4
    for (int k = 0; k < 192; ++k) {
      const float4 a = *(const float4*)&xnT[k][ty << 2];
      const float av[4] = {a.x, a.y, a.z, a.w};
#pragma unroll
      for (int m = 0; m < 2; ++m) {
        const float w = r1_w[k * 128 + tx + 64 * m];
#pragma unroll
        for (int i = 0; i < 4; ++i) a1[i][m] = fmaf(av[i], w, a1[i][m]);
      }
    }
#pragma unroll
    for (int i = 0; i < 4; ++i) {
      hT[tx][(ty << 2) + i] = gelu_f(a1[i][0]);
      hT[tx + 64][(ty << 2) + i] = gelu_f(a1[i][1]);
    }
  }
  __syncthreads();

  if (tx < 48) {
    float a2[4];
#pragma unroll
    for (int i = 0; i < 4; ++i) a2[i] = r2_b[tx];
#pragma unroll 4
    for (int k = 0; k < 128; ++k) {
      const float4 a = *(const float4*)&hT[k][ty << 2];
      const float av[4] = {a.x, a.y, a.z, a.w};
      const float w = r2_w[k * 48 + tx];
#pragma unroll
      for (int i = 0; i < 4; ++i) a2[i] = fmaf(av[i], w, a2[i]);
    }
#pragma unroll
    for (int i = 0; i < 4; ++i) rlS[(ty << 2) + i][tx] = a2[i];
  }
  __syncthreads();

  if (t < 32) {
    const int tt = t >> 1, half = t & 1;
    const float* base = &rlS[tt][half * 24];
    float v0 = -1e30f, v1 = -1e30f;
    int i0 = 0, i1 = 0;
    for (int k = 0; k < 24; ++k) {
      const float vv = base[k];
      if (vv > v0) { v1 = v0; i1 = i0; v0 = vv; i0 = k; }
      else if (vv > v1) { v1 = vv; i1 = k; }
    }
    const float tau = (float)(0.07 + 1e-8);
    const float e1 = expf((v1 - v0) / tau);
    const float inv = 1.f / (1.f + e1);
    topwS[tt][half * 2] = inv;
    topwS[tt][half * 2 + 1] = e1 * inv;
    topiS[tt][half * 2] = i0;
    topiS[tt][half * 2 + 1] = i1;
  }
  __syncthreads();

#pragma unroll
  for (int r = 0; r < 13; ++r) {
    const int f = t + 256 * r;
    if (f < 3200) {
      const int c = f >> 4, tt = f & 15;
      float val;
      if (c < 8) {
        val = topwS[tt][0] * spec_proto[topiS[tt][0] * 8 + c] +
              topwS[tt][1] * spec_proto[topiS[tt][1] * 8 + c];
      } else {
        const int cc = c - 8;
        val = topwS[tt][2] * spat_proto[topiS[tt][2] * 192 + cc] +
              topwS[tt][3] * spat_proto[topiS[tt][3] * 192 + cc];
      }
      mixT[c][tt] = val;
    }
  }
  __syncthreads();

  {
    float ak[4][3];
#pragma unroll
    for (int i = 0; i < 4; ++i)
#pragma unroll
      for (int m = 0; m < 3; ++m) ak[i][m] = pos_bias[tx + 64 * m];
#pragma unroll 4
    for (int k = 0; k < 200; ++k) {
      const float4 a = *(const float4*)&mixT[k][ty << 2];
      const float av[4] = {a.x, a.y, a.z, a.w};
#pragma unroll
      for (int m = 0; m < 3; ++m) {
        const float w = key_w[k * 192 + tx + 64 * m];
#pragma unroll
        for (int i = 0; i < 4; ++i) ak[i][m] = fmaf(av[i], w, ak[i][m]);
      }
    }
#pragma unroll
    for (int i = 0; i < 4; ++i) {
      const size_t row = ((size_t)tok0 + (ty << 2) + i) * 192;
#pragma unroll
      for (int m = 0; m < 3; ++m) keys_out[row + tx + 64 * m] = ak[i][m];
    }
  }
}

// ---------------------------------------------------------------------------
// K3a (MFMA): LN -> xn bf16 LDS; q,v = xn @ {qw,vw}; softmax(q) -> qs bf16.
// 32 tokens/block, 256 blocks, 4 waves (wm: M-tile, wn: N-half).
// ---------------------------------------------------------------------------
__global__ __launch_bounds__(256) void k3a_mfma(
    const float* __restrict__ xb, const float* __restrict__ lnw,
    const float* __restrict__ lnb, const ushort* __restrict__ qwT,
    const ushort* __restrict__ vwT, ushort* __restrict__ qs_bf,
    float* __restrict__ v_out, int depth) {
  const int t = threadIdx.x;
  const int lane = t & 63, wid = t >> 6;
  const int wm = wid >> 1, wn = wid & 1;
  const int l15 = lane & 15, lg4 = lane >> 4;
  const int tok0 = blockIdx.x * 32;

  __shared__ __align__(16) char smem[12800 + 30720];
  ushort (*s_xn)[200] = (ushort(*)[200])smem;
  ushort (*s_wq)[40] = (ushort(*)[40])(smem + 12800);
  ushort (*s_wv)[40] = (ushort(*)[40])(smem + 12800 + 15360);
  float (*s_q)[196] = (float(*)[196])(smem + 12800);

  const float* lw = lnw + depth * 192;
  const float* lb = lnb + depth * 192;
#pragma unroll
  for (int half = 0; half < 2; ++half) {
    const int tt = half * 16 + (t >> 4);
    const int lg = t & 15;
    const float* xrow = xb + ((size_t)tok0 + tt) * 192;
    float vals[12], sm = 0.f;
#pragma unroll
    for (int m = 0; m < 12; ++m) {
      vals[m] = xrow[lg + 16 * m];
      sm += vals[m];
    }
    sm = sum16(sm);
    const float mean = sm * (1.f / 192.f);
    float vv = 0.f;
#pragma unroll
    for (int m = 0; m < 12; ++m) {
      const float d0 = vals[m] - mean;
      vv = fmaf(d0, d0, vv);
    }
    vv = sum16(vv);
    const float inv = rsqrtf(vv * (1.f / 192.f) + 1e-5f);
#pragma unroll
    for (int m = 0; m < 12; ++m) {
      const int d = lg + 16 * m;
      s_xn[tt][d] = f2bf((vals[m] - mean) * inv * lw[d] + lb[d]);
    }
  }
  __syncthreads();

  f32x4 aq[6], av[6];
#pragma unroll
  for (int f = 0; f < 6; ++f) {
    aq[f] = (f32x4){0.f, 0.f, 0.f, 0.f};
    av[f] = (f32x4){0.f, 0.f, 0.f, 0.f};
  }
  const ushort* qbase = qwT + depth * 36864;
  const ushort* vbase = vwT + depth * 36864;
#pragma unroll 1
  for (int ks = 0; ks < 6; ++ks) {
#pragma unroll
    for (int i = 0; i < 3; ++i) {
      const int idx = t + 256 * i;
      const int row = idx >> 2, c4 = (idx & 3) * 8;
      *(uint4*)&s_wq[row][c4] = *(const uint4*)&qbase[row * 192 + ks * 32 + c4];
      *(uint4*)&s_wv[row][c4] = *(const uint4*)&vbase[row * 192 + ks * 32 + c4];
    }
    __syncthreads();
    const bf16x8 a = *(const bf16x8*)&s_xn[wm * 16 + l15][ks * 32 + 8 * lg4];
#pragma unroll
    for (int f = 0; f < 6; ++f) {
      const bf16x8 bq = *(const bf16x8*)&s_wq[wn * 96 + 16 * f + l15][8 * lg4];
      const bf16x8 bv = *(const bf16x8*)&s_wv[wn * 96 + 16 * f + l15][8 * lg4];
      aq[f] = __builtin_amdgcn_mfma_f32_16x16x32_bf16(a, bq, aq[f], 0, 0, 0);
      av[f] = __builtin_amdgcn_mfma_f32_16x16x32_bf16(a, bv, av[f], 0, 0, 0);
    }
    __syncthreads();
  }

  // write v (fp32), park q in LDS
  const int rl = wm * 16 + 4 * lg4;
#pragma unroll
  for (int f = 0; f < 6; ++f) {
    const int col = wn * 96 + 16 * f + l15;
#pragma unroll
    for (int reg = 0; reg < 4; ++reg) {
      v_out[((size_t)tok0 + rl + reg) * 192 + col] = av[f][reg];
      s_q[rl + reg][col] = aq[f][reg];
    }
  }
  __syncthreads();

  // softmax over q rows -> qs bf16
#pragma unroll
  for (int half = 0; half < 2; ++half) {
    const int tt = half * 16 + (t >> 4);
    const int lg = t & 15;
    float vals[12], mx = -1e30f;
#pragma unroll
    for (int m = 0; m < 12; ++m) {
      vals[m] = s_q[tt][lg + 16 * m];
      mx = fmaxf(mx, vals[m]);
    }
    mx = max16(mx);
    float s = 0.f;
#pragma unroll
    for (int m = 0; m < 12; ++m) {
      vals[m] = expf(vals[m] - mx);
      s += vals[m];
    }
    s = sum16(s);
    const float inv = 1.f / s;
#pragma unroll
    for (int m = 0; m < 12; ++m)
      qs_bf[((size_t)tok0 + tt) * 192 + lg + 16 * m] = f2bf(vals[m] * inv);
  }
}

// ---------------------------------------------------------------------------
// K3b: partial KV^T (swapped operands: A=v d-tile, B=keys) -> kvpT fp32.
// Grid: 32 b x 8 dt x 4 token-quarters = 1024 blocks.
// ---------------------------------------------------------------------------
__global__ __launch_bounds__(256) void k3b_kv(
    const float* __restrict__ va, const float* __restrict__ kb,
    float* __restrict__ kvp) {
  const int blk = blockIdx.x;
  const int ts = blk & 3;
  const int ct = (blk >> 2) & 7;
  const int b = blk >> 5;
  const int c0 = ct * 24;
  const int t = threadIdx.x;
  const int ci = t >> 6;
  const int di = t & 63;
  __shared__ float ks[16][24];
  __shared__ float vs[16][192];
  float acc[6][3];
#pragma unroll
  for (int i = 0; i < 6; ++i)
#pragma unroll
    for (int u = 0; u < 3; ++u) acc[i][u] = 0.f;

  for (int s = 0; s < 4; ++s) {
    const size_t tokbase = (size_t)b * 256 + ts * 64 + s * 16;
    if (t < 96) {
      const int nn = t / 6, u = t % 6;
      *(float4*)&ks[nn][u * 4] =
          *(const float4*)&va[(tokbase + nn) * 192 + c0 + u * 4];
    }
    {
      const float4* vp = (const float4*)(kb + tokbase * 192);
      float4* vsp = (float4*)vs;
#pragma unroll
      for (int r = 0; r < 3; ++r) vsp[t + 256 * r] = vp[t + 256 * r];
    }
    __syncthreads();
#pragma unroll 8
    for (int n = 0; n < 16; ++n) {
      float kc[6];
      *(float2*)&kc[0] = *(const float2*)&ks[n][ci * 6];
      *(float2*)&kc[2] = *(const float2*)&ks[n][ci * 6 + 2];
      *(float2*)&kc[4] = *(const float2*)&ks[n][ci * 6 + 4];
      const float vd0 = vs[n][di];
      const float vd1 = vs[n][di + 64];
      const float vd2 = vs[n][di + 128];
#pragma unroll
      for (int i = 0; i < 6; ++i) {
        acc[i][0] = fmaf(kc[i], vd0, acc[i][0]);
        acc[i][1] = fmaf(kc[i], vd1, acc[i][1]);
        acc[i][2] = fmaf(kc[i], vd2, acc[i][2]);
      }
    }
    __syncthreads();
  }
  float* outp = kvp + (size_t)ts * 1179648 + (size_t)b * 36864;
#pragma unroll
  for (int i = 0; i < 6; ++i)
#pragma unroll
    for (int u = 0; u < 3; ++u)
      outp[(c0 + ci * 6 + i) * 192 + di + 64 * u] = acc[i][u];
}

__global__ __launch_bounds__(256) void k3b_red(
    const float* __restrict__ kvp, ushort* __restrict__ kvT) {
  const int i = (blockIdx.x * 256 + threadIdx.x) * 2;
  const float s0 = kvp[i] + kvp[i + 1179648] + kvp[i + 2 * 1179648] + kvp[i + 3 * 1179648];
  const float s1 = kvp[i + 1] + kvp[i + 1 + 1179648] + kvp[i + 1 + 2 * 1179648] + kvp[i + 1 + 3 * 1179648];
  ushort2 o;
  o.x = f2bf(s0);
  o.y = f2bf(s1);
  *(ushort2*)&kvT[i] = o;
}

// ---------------------------------------------------------------------------
// K3c (MFMA): o1 = qs@KV; xbn = xb + o1*g1; LN; FFN (f1 gelu f2, half-N);
// xb = xbn + ff*g2.  32 tokens/block, 256 blocks.
// ---------------------------------------------------------------------------
__global__ __launch_bounds__(256) void k3c_mfma(
    float* __restrict__ xb, const ushort* __restrict__ qs_bf,
    const ushort* __restrict__ kvT, const float* __restrict__ lnw,
    const float* __restrict__ lnb, const ushort* __restrict__ f1T,
    const ushort* __restrict__ f2T, const float* __restrict__ f1b,
    const float* __restrict__ f2b, const float* __restrict__ g1,
    const float* __restrict__ g2, int depth) {
  const int t = threadIdx.x;
  const int lane = t & 63, wid = t >> 6;
  const int wm = wid >> 1, wn = wid & 1;
  const int l15 = lane & 15, lg4 = lane >> 4;
  const int tok0 = blockIdx.x * 32;
  const int b = blockIdx.x >> 3;

  __shared__ __align__(16) char smem[12800 + 15360 + 12800 + 512];
  ushort (*s_a)[200] = (ushort(*)[200])smem;                    // qs, then xn2
  ushort (*s_w)[40] = (ushort(*)[40])(smem + 12800);            // B staging
  ushort (*s_ff)[200] = (ushort(*)[200])(smem + 12800 + 15360); // gelu half
  float (*s_red)[4] = (float(*)[4])(smem + 12800 + 15360 + 12800);

  // stage qs tile
#pragma unroll
  for (int i = 0; i < 3; ++i) {
    const int idx = t + 256 * i;
    const int row = idx / 24, c8 = (idx % 24) * 8;
    *(uint4*)&s_a[row][c8] = *(const uint4*)&qs_bf[((size_t)tok0 + row) * 192 + c8];
  }
  __syncthreads();

  // o1 = qs @ KV   (B from kvT[d][c], k-contiguous in c)
  f32x4 o1[6];
#pragma unroll
  for (int f = 0; f < 6; ++f) o1[f] = (f32x4){0.f, 0.f, 0.f, 0.f};
  const ushort* kvb = kvT + (size_t)b * 36864;
#pragma unroll 1
  for (int ks = 0; ks < 6; ++ks) {
#pragma unroll
    for (int i = 0; i < 3; ++i) {
      const int idx = t + 256 * i;
      const int row = idx >> 2, c4 = (idx & 3) * 8;
      *(uint4*)&s_w[row][c4] = *(const uint4*)&kvb[row * 192 + ks * 32 + c4];
    }
    __syncthreads();
    const bf16x8 a = *(const bf16x8*)&s_a[wm * 16 + l15][ks * 32 + 8 * lg4];
#pragma unroll
    for (int f = 0; f < 6; ++f) {
      const bf16x8 bb = *(const bf16x8*)&s_w[wn * 96 + 16 * f + l15][8 * lg4];
      o1[f] = __builtin_amdgcn_mfma_f32_16x16x32_bf16(a, bb, o1[f], 0, 0, 0);
    }
    __syncthreads();
  }

  // residual 1 + LN stats
  const float* g1p = g1 + depth * 192;
  const float* lw = lnw + depth * 192;
  const float* lb = lnb + depth * 192;
  const int rl = wm * 16 + 4 * lg4;
  float xbn[6][4];
  float psum[4] = {0.f, 0.f, 0.f, 0.f}, psq[4] = {0.f, 0.f, 0.f, 0.f};
#pragma unroll
  for (int f = 0; f < 6; ++f) {
    const int col = wn * 96 + 16 * f + l15;
#pragma unroll
    for (int reg = 0; reg < 4; ++reg) {
      const float xv =
          xb[((size_t)tok0 + rl + reg) * 192 + col] + o1[f][reg] * g1p[col];
      xbn[f][reg] = xv;
      psum[reg] += xv;
      psq[reg] = fmaf(xv, xv, psq[reg]);
    }
  }
#pragma unroll
  for (int reg = 0; reg < 4; ++reg) {
#pragma unroll
    for (int o = 8; o > 0; o >>= 1) {
      psum[reg] += __shfl_xor(psum[reg], o, 64);
      psq[reg] += __shfl_xor(psq[reg], o, 64);
    }
  }
  if (l15 == 0) {
#pragma unroll
    for (int reg = 0; reg < 4; ++reg) {
      s_red[rl + reg][wn] = psum[reg];
      s_red[rl + reg][2 + wn] = psq[reg];
    }
  }
  __syncthreads();
  float mean[4], inv[4];
#pragma unroll
  for (int reg = 0; reg < 4; ++reg) {
    const float s = s_red[rl + reg][0] + s_red[rl + reg][1];
    const float q = s_red[rl + reg][2] + s_red[rl + reg][3];
    mean[reg] = s * (1.f / 192.f);
    const float var = q * (1.f / 192.f) - mean[reg] * mean[reg];
    inv[reg] = rsqrtf(var + 1e-5f);
  }
  // xn2 -> s_a (bf16), overwrite qs
#pragma unroll
  for (int f = 0; f < 6; ++f) {
    const int col = wn * 96 + 16 * f + l15;
#pragma unroll
    for (int reg = 0; reg < 4; ++reg)
      s_a[rl + reg][col] =
          f2bf((xbn[f][reg] - mean[reg]) * inv[reg] * lw[col] + lb[col]);
  }
  __syncthreads();

  // FFN: two N-halves of f1, interleaved with K-halves of f2
  f32x4 o2[6];
#pragma unroll
  for (int f = 0; f < 6; ++f) o2[f] = (f32x4){0.f, 0.f, 0.f, 0.f};
#pragma unroll 1
  for (int h = 0; h < 2; ++h) {
    f32x4 hh[6];
#pragma unroll
    for (int f = 0; f < 6; ++f) hh[f] = (f32x4){0.f, 0.f, 0.f, 0.f};
    const ushort* f1base = f1T + depth * 73728 + h * 36864;
#pragma unroll 1
    for (int ks = 0; ks < 6; ++ks) {
#pragma unroll
      for (int i = 0; i < 3; ++i) {
        const int idx = t + 256 * i;
        const int row = idx >> 2, c4 = (idx & 3) * 8;
        *(uint4*)&s_w[row][c4] = *(const uint4*)&f1base[row * 192 + ks * 32 + c4];
      }
      __syncthreads();
      const bf16x8 a = *(const bf16x8*)&s_a[wm * 16 + l15][ks * 32 + 8 * lg4];
#pragma unroll
      for (int f = 0; f < 6; ++f) {
        const bf16x8 bb = *(const bf16x8*)&s_w[wn * 96 + 16 * f + l15][8 * lg4];
        hh[f] = __builtin_amdgcn_mfma_f32_16x16x32_bf16(a, bb, hh[f], 0, 0, 0);
      }
      __syncthreads();
    }
    const float* b1p = f1b + depth * 384 + h * 192;
#pragma unroll
    for (int f = 0; f < 6; ++f) {
      const int col = wn * 96 + 16 * f + l15;
#pragma unroll
      for (int reg = 0; reg < 4; ++reg)
        s_ff[rl + reg][col] = f2bf(gelu_f(hh[f][reg] + b1p[col]));
    }
    __syncthreads();
    const ushort* f2base = f2T + depth * 73728;
#pragma unroll 1
    for (int ks2 = 0; ks2 < 6; ++ks2) {
#pragma unroll
      for (int i = 0; i < 3; ++i) {
        const int idx = t + 256 * i;
        const int row = idx >> 2, c4 = (idx & 3) * 8;
        *(uint4*)&s_w[row][c4] =
            *(const uint4*)&f2base[row * 384 + h * 192 + ks2 * 32 + c4];
      }
      __syncthreads();
      const bf16x8 a = *(const bf16x8*)&s_ff[wm * 16 + l15][ks2 * 32 + 8 * lg4];
#pragma unroll
      for (int f = 0; f < 6; ++f) {
        const bf16x8 bb = *(const bf16x8*)&s_w[wn * 96 + 16 * f + l15][8 * lg4];
        o2[f] = __builtin_amdgcn_mfma_f32_16x16x32_bf16(a, bb, o2[f], 0, 0, 0);
      }
      __syncthreads();
    }
  }

  // final residual
  const float* b2p = f2b + depth * 192;
  const float* g2p = g2 + depth * 192;
#pragma unroll
  for (int f = 0; f < 6; ++f) {
    const int col = wn * 96 + 16 * f + l15;
#pragma unroll
    for (int reg = 0; reg < 4; ++reg)
      xb[((size_t)tok0 + rl + reg) * 192 + col] =
          xbn[f][reg] + (o2[f][reg] + b2p[col]) * g2p[col];
  }
}

// ---------------------------------------------------------------------------
// K4: feat = LN(mean_n xb); out = feat @ head_w + head_b.
// ---------------------------------------------------------------------------
__global__ __launch_bounds__(192) void k4_head(
    const float* __restrict__ xb, const float* __restrict__ flnw,
    const float* __restrict__ flnb, const float* __restrict__ hw,
    const float* __restrict__ hb, float* __restrict__ out) {
  const int b = blockIdx.x, t = threadIdx.x;
  const int w = t >> 6, lane = t & 63;
  float s = 0.f;
  const float* base = xb + (size_t)b * 256 * 192 + t;
#pragma unroll 4
  for (int n = 0; n < 256; ++n) s += base[n * 192];
  const float feat_pre = s * (1.f / 256.f);
  __shared__ float red[3];
  __shared__ float feat[192];
  float sm = wsum64(feat_pre);
  if (lane == 0) red[w] = sm;
  __syncthreads();
  const float mean = (red[0] + red[1] + red[2]) * (1.f / 192.f);
  __syncthreads();
  const float dd = feat_pre - mean;
  sm = wsum64(dd * dd);
  if (lane == 0) red[w] = sm;
  __syncthreads();
  const float var = (red[0] + red[1] + red[2]) * (1.f / 192.f);
  feat[t] = dd * rsqrtf(var + 1e-5f) * flnw[t] + flnb[t];
  __syncthreads();
  if (t < 9) {
    float a = hb[t];
    for (int d = 0; d < 192; ++d) a = fmaf(feat[d], hw[d * 9 + t], a);
    out[b * 9 + t] = a;
  }
}

// ---------------------------------------------------------------------------
extern "C" void kernel_launch(void* const* d_in, const int* in_sizes, int n_in,
                              void* d_out, int out_size, void* d_ws, size_t ws_size,
                              hipStream_t stream) {
  (void)in_sizes; (void)n_in; (void)out_size; (void)ws_size;
  const float* x          = (const float*)d_in[0];
  const float* band_w     = (const float*)d_in[1];
  const float* band_b     = (const float*)d_in[2];
  const float* dw_w       = (const float*)d_in[3];
  const float* pw_w       = (const float*)d_in[4];
  const float* pe_ln_w    = (const float*)d_in[5];
  const float* pe_ln_b    = (const float*)d_in[6];
  const float* spec_proto = (const float*)d_in[7];
  const float* spat_proto = (const float*)d_in[8];
  const float* r1_w       = (const float*)d_in[9];
  const float* r1_b       = (const float*)d_in[10];
  const float* r2_w       = (const float*)d_in[11];
  const float* r2_b       = (const float*)d_in[12];
  const float* key_w      = (const float*)d_in[13];
  const float* pos_bias   = (const float*)d_in[14];
  const float* blk_ln_w   = (const float*)d_in[15];
  const float* blk_ln_b   = (const float*)d_in[16];
  const float* blk_q_w    = (const float*)d_in[17];
  const float* blk_v_w    = (const float*)d_in[18];
  const float* blk_f1_w   = (const float*)d_in[19];
  const float* blk_f1_b   = (const float*)d_in[20];
  const float* blk_f2_w   = (const float*)d_in[21];
  const float* blk_f2_b   = (const float*)d_in[22];
  const float* blk_g1     = (const float*)d_in[23];
  const float* blk_g2     = (const float*)d_in[24];
  const float* fin_ln_w   = (const float*)d_in[25];
  const float* fin_ln_b   = (const float*)d_in[26];
  const float* head_w     = (const float*)d_in[27];
  const float* head_b     = (const float*)d_in[28];

  float* ws   = (float*)d_ws;
  float* dw   = ws;                    //    65,536 f32
  float* xbuf = dw + 65536;            // 1,572,864 f32
  float* keys = xbuf + 1572864;        // 1,572,864 f32
  float* vbuf = keys + 1572864;        // 1,572,864 f32
  float* kvp  = vbuf + 1572864;        // 4,718,592 f32
  ushort* ush   = (ushort*)(kvp + 4718592);
  ushort* qs_bf = ush;                 // 1,572,864 ush
  ushort* kvT   = qs_bf + 1572864;     // 1,179,648 ush
  ushort* qwT   = kvT + 1179648;       //   110,592 ush
  ushort* vwT   = qwT + 110592;        //   110,592 ush
  ushort* f1T   = vwT + 110592;        //   221,184 ush
  ushort* f2T   = f1T + 221184;        //   221,184 ush

  prep_w<<<864, 256, 0, stream>>>(blk_q_w, blk_v_w, blk_f1_w, blk_f2_w,
                                  qwT, vwT, f1T, f2T);
  k1_band_dw<<<512, 512, 0, stream>>>(x, band_w, band_b, dw_w, dw);
  k2_token<<<512, 256, 0, stream>>>(dw, pw_w, pe_ln_w, pe_ln_b, spec_proto,
                                    spat_proto, r1_w, r1_b, r2_w, r2_b, key_w,
                                    pos_bias, xbuf, keys);
  for (int d = 0; d < 3; ++d) {
    k3a_mfma<<<256, 256, 0, stream>>>(xbuf, blk_ln_w, blk_ln_b, qwT, vwT,
                                      qs_bf, vbuf, d);
    k3b_kv<<<1024, 256, 0, stream>>>(vbuf, keys, kvp);
    k3b_red<<<2304, 256, 0, stream>>>(kvp, kvT);
    k3c_mfma<<<256, 256, 0, stream>>>(xbuf, qs_bf, kvT, blk_ln_w, blk_ln_b,
                                      f1T, f2T, blk_f1_b, blk_f2_b, blk_g1,
                                      blk_g2, d);
  }
  k4_head<<<32, 192, 0, stream>>>(xbuf, fin_ln_w, fin_ln_b, head_w, head_b,
                                  (float*)d_out);
}

// Round 4
// 406.914 us; speedup vs baseline: 1.9881x; 1.1093x over previous
//
#include <hip/hip_runtime.h>
#include <math.h>

// ---------------------------------------------------------------------------
// OptimizedProtoHyperFormer — round 4: K1 latency fixes + K2 MFMA.
// B=32, IB=103, H=W=256, P=16, RB=8, DIM=192, DEPTH=3, FFH=384, NT=8192.
// ---------------------------------------------------------------------------

typedef __attribute__((ext_vector_type(8))) short bf16x8;
typedef __attribute__((ext_vector_type(4))) float f32x4;

__device__ __forceinline__ float wsum64(float v) {
#pragma unroll
  for (int o = 32; o > 0; o >>= 1) v += __shfl_xor(v, o, 64);
  return v;
}
__device__ __forceinline__ float sum16(float v) {
#pragma unroll
  for (int o = 8; o > 0; o >>= 1) v += __shfl_xor(v, o, 64);
  return v;
}
__device__ __forceinline__ float max16(float v) {
#pragma unroll
  for (int o = 8; o > 0; o >>= 1) v = fmaxf(v, __shfl_xor(v, o, 64));
  return v;
}
__device__ __forceinline__ float gelu_f(float x) {
  return 0.5f * x * (1.0f + erff(x * 0.7071067811865476f));
}
__device__ __forceinline__ ushort f2bf(float f) {
  union { float f; unsigned u; } v;
  v.f = f;
  unsigned r = v.u + 0x7FFFu + ((v.u >> 16) & 1u);
  return (ushort)(r >> 16);
}

// ---------------------------------------------------------------------------
// prep: bf16 transposes of all MFMA weights + band_w transpose.
// ---------------------------------------------------------------------------
__global__ __launch_bounds__(256) void prep_w(
    const float* __restrict__ qw, const float* __restrict__ vw,
    const float* __restrict__ f1w, const float* __restrict__ f2w,
    const float* __restrict__ r1_w, const float* __restrict__ r2_w,
    const float* __restrict__ key_w, const float* __restrict__ band_w,
    ushort* __restrict__ qwT, ushort* __restrict__ vwT,
    ushort* __restrict__ f1T, ushort* __restrict__ f2T,
    ushort* __restrict__ r1T, ushort* __restrict__ r2T,
    ushort* __restrict__ keyT, float* __restrict__ bandT) {
  const int i = blockIdx.x * 256 + threadIdx.x;
  if (i < 110592) {  // qw, vw: [3][192][192] -> [3][j][k]
    const int d = i / 36864, r = i % 36864;
    const int k = r / 192, c = r % 192;
    qwT[d * 36864 + c * 192 + k] = f2bf(qw[i]);
    vwT[d * 36864 + c * 192 + k] = f2bf(vw[i]);
  }
  if (i < 221184) {
    const int d = i / 73728, r = i % 73728;
    const int k = r / 384, j = r % 384;        // f1: [3][192][384] -> [3][384][192]
    f1T[d * 73728 + j * 192 + k] = f2bf(f1w[i]);
    const int k2 = r / 192, j2 = r % 192;      // f2: [3][384][192] -> [3][192][384]
    f2T[d * 73728 + j2 * 384 + k2] = f2bf(f2w[i]);
  }
  if (i < 24576) {  // r1: [192][128] -> [j:128][k:192]
    const int j = i / 192, k = i % 192;
    r1T[i] = f2bf(r1_w[k * 128 + j]);
  }
  if (i < 6144) {   // r2: [128][48] -> [j:48][k:128]
    const int j = i / 128, k = i % 128;
    r2T[i] = f2bf(r2_w[k * 48 + j]);
  }
  if (i < 43008) {  // key: [200][192] -> [j:192][k:224 padded]
    const int j = i / 224, k = i % 224;
    keyT[i] = (k < 200) ? f2bf(key_w[k * 192 + j]) : (ushort)0;
  }
  if (i < 824) {    // band_w: [8][103] -> [103][8]
    const int ch = i >> 3, c = i & 7;
    bandT[i] = band_w[c * 103 + ch];
  }
}

// ---------------------------------------------------------------------------
// K1: fused band-reduction (103->8) + depthwise patch conv.
// 512 blocks (batch x patch-row), 512 threads. Unroll-2, prefetch distance 2,
// bandT gives one uniform 32B scalar load per channel.
// ---------------------------------------------------------------------------
__global__ __launch_bounds__(512) void k1_band_dw(
    const float* __restrict__ x, const float* __restrict__ bandT,
    const float* __restrict__ band_b, const float* __restrict__ dw_w,
    float* __restrict__ dw_out) {
  const int blk = blockIdx.x;
  const int b = blk >> 4, ip = blk & 15;
  const int t = threadIdx.x;
  const int col4 = t & 63;
  const int j = col4 >> 2;
  const int qb = (col4 & 3) << 2;
  const int p0 = t >> 6;

  float acc[8][8];
#pragma unroll
  for (int e = 0; e < 8; ++e)
#pragma unroll
    for (int c = 0; c < 8; ++c) acc[e][c] = 0.f;

  const float4* xp = (const float4*)x + (size_t)b * (103 * 16384) + (size_t)ip * 1024;

  auto body = [&](const float4 v0, const float4 v1, const int ch) {
    const float4 wA = *(const float4*)&bandT[ch * 8];
    const float4 wB = *(const float4*)&bandT[ch * 8 + 4];
    const float bw[8] = {wA.x, wA.y, wA.z, wA.w, wB.x, wB.y, wB.z, wB.w};
#pragma unroll
    for (int c = 0; c < 8; ++c) {
      acc[0][c] = fmaf(v0.x, bw[c], acc[0][c]);
      acc[1][c] = fmaf(v0.y, bw[c], acc[1][c]);
      acc[2][c] = fmaf(v0.z, bw[c], acc[2][c]);
      acc[3][c] = fmaf(v0.w, bw[c], acc[3][c]);
      acc[4][c] = fmaf(v1.x, bw[c], acc[4][c]);
      acc[5][c] = fmaf(v1.y, bw[c], acc[5][c]);
      acc[6][c] = fmaf(v1.z, bw[c], acc[6][c]);
      acc[7][c] = fmaf(v1.w, bw[c], acc[7][c]);
    }
  };

  float4 p0v = xp[t], p1v = xp[t + 512];              // ch
  float4 q0v = xp[t + 16384], q1v = xp[t + 16896];    // ch+1
#pragma unroll 1
  for (int ch = 0; ch < 100; ch += 2) {
    const float4 r0 = xp[t + 2 * 16384], r1 = xp[t + 2 * 16384 + 512];
    const float4 s0 = xp[t + 3 * 16384], s1 = xp[t + 3 * 16384 + 512];
    body(p0v, p1v, ch);
    body(q0v, q1v, ch + 1);
    p0v = r0; p1v = r1; q0v = s0; q1v = s1;
    xp += 2 * 16384;
  }
  const float4 u0 = xp[t + 2 * 16384], u1 = xp[t + 2 * 16384 + 512];
  body(p0v, p1v, 100);
  body(q0v, q1v, 101);
  body(u0, u1, 102);

  float dwt[8];
#pragma unroll
  for (int c = 0; c < 8; ++c) dwt[c] = 0.f;
#pragma unroll
  for (int e = 0; e < 8; ++e) {
    const int pp = p0 + ((e >> 2) << 3);
    const int qq = qb + (e & 3);
#pragma unroll
    for (int c = 0; c < 8; ++c)
      dwt[c] = fmaf(dw_w[c * 256 + pp * 16 + qq], acc[e][c] + band_b[c], dwt[c]);
  }
#pragma unroll
  for (int c = 0; c < 8; ++c) {
    dwt[c] += __shfl_xor(dwt[c], 1, 64);
    dwt[c] += __shfl_xor(dwt[c], 2, 64);
  }
  __shared__ float part[8][16][8];
  if ((t & 3) == 0) {
#pragma unroll
    for (int c = 0; c < 8; ++c) part[t >> 6][j][c] = dwt[c];
  }
  __syncthreads();
  if (t < 128) {
    const int jj = t >> 3, c = t & 7;
    float s = 0.f;
#pragma unroll
    for (int w = 0; w < 8; ++w) s += part[w][jj][c];
    dw_out[(((size_t)b * 16 + ip) * 16 + jj) * 8 + c] = s;
  }
}

// ---------------------------------------------------------------------------
// K2 (MFMA): pw+LN -> router r1/r2 -> top2 -> proto mix -> keys.
// 32 tokens/block, 256 blocks, 4 waves (wm: token half, wn: N half).
// ---------------------------------------------------------------------------
__global__ __launch_bounds__(256) void k2_mfma(
    const float* __restrict__ dw, const float* __restrict__ pw_w,
    const float* __restrict__ pe_ln_w, const float* __restrict__ pe_ln_b,
    const float* __restrict__ spec_proto, const float* __restrict__ spat_proto,
    const ushort* __restrict__ r1T, const float* __restrict__ r1_b,
    const ushort* __restrict__ r2T, const float* __restrict__ r2_b,
    const ushort* __restrict__ keyT, const float* __restrict__ pos_bias,
    float* __restrict__ xb_out, float* __restrict__ keys_out) {
  const int t = threadIdx.x;
  const int lane = t & 63, wid = t >> 6;
  const int wm = wid >> 1, wn = wid & 1;
  const int l15 = lane & 15, lg4 = lane >> 4;
  const int tok0 = blockIdx.x * 32;
  const int rl = wm * 16 + 4 * lg4;

  __shared__ float dw8s[32][8];
  __shared__ __align__(16) ushort s_xn[32][200];
  __shared__ __align__(16) ushort s_w[192][40];
  __shared__ __align__(16) ushort s_h[32][200];
  __shared__ __align__(16) ushort s_mix[32][232];
  __shared__ float s_rl[32][48];
  __shared__ float topwS[32][4];
  __shared__ int   topiS[32][4];

  dw8s[t >> 3][t & 7] = dw[((size_t)tok0 + (t >> 3)) * 8 + (t & 7)];
  __syncthreads();

  // ---- phase 1: pw + LN -> xb fp32, s_xn bf16 ----
#pragma unroll
  for (int half = 0; half < 2; ++half) {
    const int tt = half * 16 + (t >> 4), lg = t & 15;
    float pre[12], sm = 0.f;
#pragma unroll
    for (int m = 0; m < 12; ++m) {
      const int d = lg + 16 * m;
      const float4 pa = *(const float4*)&pw_w[d * 8];
      const float4 pb = *(const float4*)&pw_w[d * 8 + 4];
      float p = pa.x * dw8s[tt][0] + pa.y * dw8s[tt][1] + pa.z * dw8s[tt][2] +
                pa.w * dw8s[tt][3] + pb.x * dw8s[tt][4] + pb.y * dw8s[tt][5] +
                pb.z * dw8s[tt][6] + pb.w * dw8s[tt][7];
      pre[m] = p;
      sm += p;
    }
    sm = sum16(sm);
    const float mean = sm * (1.f / 192.f);
    float vv = 0.f;
#pragma unroll
    for (int m = 0; m < 12; ++m) {
      const float d0 = pre[m] - mean;
      vv = fmaf(d0, d0, vv);
    }
    vv = sum16(vv);
    const float inv = rsqrtf(vv * (1.f / 192.f) + 1e-5f);
#pragma unroll
    for (int m = 0; m < 12; ++m) {
      const int d = lg + 16 * m;
      const float xv = (pre[m] - mean) * inv * pe_ln_w[d] + pe_ln_b[d];
      s_xn[tt][d] = f2bf(xv);
      xb_out[((size_t)tok0 + tt) * 192 + d] = xv;
    }
  }
  __syncthreads();

  // ---- phase 2: r1 (K=192 -> 128) + gelu -> s_h bf16 ----
  {
    f32x4 hacc[4];
#pragma unroll
    for (int f = 0; f < 4; ++f) hacc[f] = (f32x4){0.f, 0.f, 0.f, 0.f};
#pragma unroll 1
    for (int ks = 0; ks < 6; ++ks) {
#pragma unroll
      for (int i = 0; i < 2; ++i) {
        const int lin = t + 256 * i;
        const int row = lin >> 2, c8 = (lin & 3) * 8;
        *(uint4*)&s_w[row][c8] = *(const uint4*)&r1T[row * 192 + ks * 32 + c8];
      }
      __syncthreads();
      const bf16x8 a = *(const bf16x8*)&s_xn[wm * 16 + l15][ks * 32 + 8 * lg4];
#pragma unroll
      for (int f = 0; f < 4; ++f) {
        const bf16x8 bb = *(const bf16x8*)&s_w[wn * 64 + 16 * f + l15][8 * lg4];
        hacc[f] = __builtin_amdgcn_mfma_f32_16x16x32_bf16(a, bb, hacc[f], 0, 0, 0);
      }
      __syncthreads();
    }
#pragma unroll
    for (int f = 0; f < 4; ++f) {
      const int col = wn * 64 + 16 * f + l15;
#pragma unroll
      for (int reg = 0; reg < 4; ++reg)
        s_h[rl + reg][col] = f2bf(gelu_f(hacc[f][reg] + r1_b[col]));
    }
  }
  __syncthreads();

  // ---- phase 3: r2 (K=128 -> 48) -> s_rl fp32 ----
  {
    f32x4 racc[2];
    racc[0] = (f32x4){0.f, 0.f, 0.f, 0.f};
    racc[1] = (f32x4){0.f, 0.f, 0.f, 0.f};
#pragma unroll 1
    for (int ks = 0; ks < 4; ++ks) {
      if (t < 192) {
        const int row = t >> 2, c8 = (t & 3) * 8;
        *(uint4*)&s_w[row][c8] = *(const uint4*)&r2T[row * 128 + ks * 32 + c8];
      }
      __syncthreads();
      const bf16x8 a = *(const bf16x8*)&s_h[wm * 16 + l15][ks * 32 + 8 * lg4];
      if (wn == 0) {
#pragma unroll
        for (int f = 0; f < 2; ++f) {
          const bf16x8 bb = *(const bf16x8*)&s_w[16 * f + l15][8 * lg4];
          racc[f] = __builtin_amdgcn_mfma_f32_16x16x32_bf16(a, bb, racc[f], 0, 0, 0);
        }
      } else {
        const bf16x8 bb = *(const bf16x8*)&s_w[32 + l15][8 * lg4];
        racc[0] = __builtin_amdgcn_mfma_f32_16x16x32_bf16(a, bb, racc[0], 0, 0, 0);
      }
      __syncthreads();
    }
    if (wn == 0) {
#pragma unroll
      for (int f = 0; f < 2; ++f) {
        const int col = 16 * f + l15;
#pragma unroll
        for (int reg = 0; reg < 4; ++reg)
          s_rl[rl + reg][col] = racc[f][reg] + r2_b[col];
      }
    } else {
      const int col = 32 + l15;
#pragma unroll
      for (int reg = 0; reg < 4; ++reg)
        s_rl[rl + reg][col] = racc[0][reg] + r2_b[col];
    }
  }
  __syncthreads();

  // ---- phase 4: top-2 + tau softmax (fp32) ----
  if (t < 64) {
    const int tt = t >> 1, half = t & 1;
    const float* base = &s_rl[tt][half * 24];
    float v0 = -1e30f, v1 = -1e30f;
    int i0 = 0, i1 = 0;
    for (int k = 0; k < 24; ++k) {
      const float vv = base[k];
      if (vv > v0) { v1 = v0; i1 = i0; v0 = vv; i0 = k; }
      else if (vv > v1) { v1 = vv; i1 = k; }
    }
    const float tau = (float)(0.07 + 1e-8);
    const float e1 = expf((v1 - v0) / tau);
    const float inv = 1.f / (1.f + e1);
    topwS[tt][half * 2] = inv;
    topwS[tt][half * 2 + 1] = e1 * inv;
    topiS[tt][half * 2] = i0;
    topiS[tt][half * 2 + 1] = i1;
  }
  __syncthreads();

  // ---- phase 5: mixed prototypes s_mix[32][224 padded] bf16 ----
#pragma unroll
  for (int r = 0; r < 28; ++r) {
    const int f = t + 256 * r;  // 32*224 = 7168 exact
    const int tok = f / 224, c = f % 224;
    float val = 0.f;
    if (c < 8) {
      val = topwS[tok][0] * spec_proto[topiS[tok][0] * 8 + c] +
            topwS[tok][1] * spec_proto[topiS[tok][1] * 8 + c];
    } else if (c < 200) {
      const int cc = c - 8;
      val = topwS[tok][2] * spat_proto[topiS[tok][2] * 192 + cc] +
            topwS[tok][3] * spat_proto[topiS[tok][3] * 192 + cc];
    }
    s_mix[tok][c] = f2bf(val);
  }
  __syncthreads();

  // ---- phase 6: keys (K=224 -> 192) + pos_bias ----
  {
    f32x4 kacc[6];
#pragma unroll
    for (int f = 0; f < 6; ++f) kacc[f] = (f32x4){0.f, 0.f, 0.f, 0.f};
#pragma unroll 1
    for (int ks = 0; ks < 7; ++ks) {
#pragma unroll
      for (int i = 0; i < 3; ++i) {
        const int lin = t + 256 * i;
        const int row = lin >> 2, c8 = (lin & 3) * 8;
        *(uint4*)&s_w[row][c8] = *(const uint4*)&keyT[row * 224 + ks * 32 + c8];
      }
      __syncthreads();
      const bf16x8 a = *(const bf16x8*)&s_mix[wm * 16 + l15][ks * 32 + 8 * lg4];
#pragma unroll
      for (int f = 0; f < 6; ++f) {
        const bf16x8 bb = *(const bf16x8*)&s_w[wn * 96 + 16 * f + l15][8 * lg4];
        kacc[f] = __builtin_amdgcn_mfma_f32_16x16x32_bf16(a, bb, kacc[f], 0, 0, 0);
      }
      __syncthreads();
    }
#pragma unroll
    for (int f = 0; f < 6; ++f) {
      const int col = wn * 96 + 16 * f + l15;
#pragma unroll
      for (int reg = 0; reg < 4; ++reg)
        keys_out[((size_t)tok0 + rl + reg) * 192 + col] = kacc[f][reg] + pos_bias[col];
    }
  }
}

// ---------------------------------------------------------------------------
// K3a (MFMA): LN -> xn bf16 LDS; q,v; softmax(q) -> qs bf16. Unchanged.
// ---------------------------------------------------------------------------
__global__ __launch_bounds__(256) void k3a_mfma(
    const float* __restrict__ xb, const float* __restrict__ lnw,
    const float* __restrict__ lnb, const ushort* __restrict__ qwT,
    const ushort* __restrict__ vwT, ushort* __restrict__ qs_bf,
    float* __restrict__ v_out, int depth) {
  const int t = threadIdx.x;
  const int lane = t & 63, wid = t >> 6;
  const int wm = wid >> 1, wn = wid & 1;
  const int l15 = lane & 15, lg4 = lane >> 4;
  const int tok0 = blockIdx.x * 32;

  __shared__ __align__(16) char smem[12800 + 30720];
  ushort (*s_xn)[200] = (ushort(*)[200])smem;
  ushort (*s_wq)[40] = (ushort(*)[40])(smem + 12800);
  ushort (*s_wv)[40] = (ushort(*)[40])(smem + 12800 + 15360);
  float (*s_q)[196] = (float(*)[196])(smem + 12800);

  const float* lw = lnw + depth * 192;
  const float* lb = lnb + depth * 192;
#pragma unroll
  for (int half = 0; half < 2; ++half) {
    const int tt = half * 16 + (t >> 4);
    const int lg = t & 15;
    const float* xrow = xb + ((size_t)tok0 + tt) * 192;
    float vals[12], sm = 0.f;
#pragma unroll
    for (int m = 0; m < 12; ++m) {
      vals[m] = xrow[lg + 16 * m];
      sm += vals[m];
    }
    sm = sum16(sm);
    const float mean = sm * (1.f / 192.f);
    float vv = 0.f;
#pragma unroll
    for (int m = 0; m < 12; ++m) {
      const float d0 = vals[m] - mean;
      vv = fmaf(d0, d0, vv);
    }
    vv = sum16(vv);
    const float inv = rsqrtf(vv * (1.f / 192.f) + 1e-5f);
#pragma unroll
    for (int m = 0; m < 12; ++m) {
      const int d = lg + 16 * m;
      s_xn[tt][d] = f2bf((vals[m] - mean) * inv * lw[d] + lb[d]);
    }
  }
  __syncthreads();

  f32x4 aq[6], av[6];
#pragma unroll
  for (int f = 0; f < 6; ++f) {
    aq[f] = (f32x4){0.f, 0.f, 0.f, 0.f};
    av[f] = (f32x4){0.f, 0.f, 0.f, 0.f};
  }
  const ushort* qbase = qwT + depth * 36864;
  const ushort* vbase = vwT + depth * 36864;
#pragma unroll 1
  for (int ks = 0; ks < 6; ++ks) {
#pragma unroll
    for (int i = 0; i < 3; ++i) {
      const int idx = t + 256 * i;
      const int row = idx >> 2, c4 = (idx & 3) * 8;
      *(uint4*)&s_wq[row][c4] = *(const uint4*)&qbase[row * 192 + ks * 32 + c4];
      *(uint4*)&s_wv[row][c4] = *(const uint4*)&vbase[row * 192 + ks * 32 + c4];
    }
    __syncthreads();
    const bf16x8 a = *(const bf16x8*)&s_xn[wm * 16 + l15][ks * 32 + 8 * lg4];
#pragma unroll
    for (int f = 0; f < 6; ++f) {
      const bf16x8 bq = *(const bf16x8*)&s_wq[wn * 96 + 16 * f + l15][8 * lg4];
      const bf16x8 bv = *(const bf16x8*)&s_wv[wn * 96 + 16 * f + l15][8 * lg4];
      aq[f] = __builtin_amdgcn_mfma_f32_16x16x32_bf16(a, bq, aq[f], 0, 0, 0);
      av[f] = __builtin_amdgcn_mfma_f32_16x16x32_bf16(a, bv, av[f], 0, 0, 0);
    }
    __syncthreads();
  }

  const int rl = wm * 16 + 4 * lg4;
#pragma unroll
  for (int f = 0; f < 6; ++f) {
    const int col = wn * 96 + 16 * f + l15;
#pragma unroll
    for (int reg = 0; reg < 4; ++reg) {
      v_out[((size_t)tok0 + rl + reg) * 192 + col] = av[f][reg];
      s_q[rl + reg][col] = aq[f][reg];
    }
  }
  __syncthreads();

#pragma unroll
  for (int half = 0; half < 2; ++half) {
    const int tt = half * 16 + (t >> 4);
    const int lg = t & 15;
    float vals[12], mx = -1e30f;
#pragma unroll
    for (int m = 0; m < 12; ++m) {
      vals[m] = s_q[tt][lg + 16 * m];
      mx = fmaxf(mx, vals[m]);
    }
    mx = max16(mx);
    float s = 0.f;
#pragma unroll
    for (int m = 0; m < 12; ++m) {
      vals[m] = expf(vals[m] - mx);
      s += vals[m];
    }
    s = sum16(s);
    const float inv = 1.f / s;
#pragma unroll
    for (int m = 0; m < 12; ++m)
      qs_bf[((size_t)tok0 + tt) * 192 + lg + 16 * m] = f2bf(vals[m] * inv);
  }
}

// ---------------------------------------------------------------------------
// K3b: partial KV^T. Unchanged.
// ---------------------------------------------------------------------------
__global__ __launch_bounds__(256) void k3b_kv(
    const float* __restrict__ va, const float* __restrict__ kb,
    float* __restrict__ kvp) {
  const int blk = blockIdx.x;
  const int ts = blk & 3;
  const int ct = (blk >> 2) & 7;
  const int b = blk >> 5;
  const int c0 = ct * 24;
  const int t = threadIdx.x;
  const int ci = t >> 6;
  const int di = t & 63;
  __shared__ float ks[16][24];
  __shared__ float vs[16][192];
  float acc[6][3];
#pragma unroll
  for (int i = 0; i < 6; ++i)
#pragma unroll
    for (int u = 0; u < 3; ++u) acc[i][u] = 0.f;

  for (int s = 0; s < 4; ++s) {
    const size_t tokbase = (size_t)b * 256 + ts * 64 + s * 16;
    if (t < 96) {
      const int nn = t / 6, u = t % 6;
      *(float4*)&ks[nn][u * 4] =
          *(const float4*)&va[(tokbase + nn) * 192 + c0 + u * 4];
    }
    {
      const float4* vp = (const float4*)(kb + tokbase * 192);
      float4* vsp = (float4*)vs;
#pragma unroll
      for (int r = 0; r < 3; ++r) vsp[t + 256 * r] = vp[t + 256 * r];
    }
    __syncthreads();
#pragma unroll 8
    for (int n = 0; n < 16; ++n) {
      float kc[6];
      *(float2*)&kc[0] = *(const float2*)&ks[n][ci * 6];
      *(float2*)&kc[2] = *(const float2*)&ks[n][ci * 6 + 2];
      *(float2*)&kc[4] = *(const float2*)&ks[n][ci * 6 + 4];
      const float vd0 = vs[n][di];
      const float vd1 = vs[n][di + 64];
      const float vd2 = vs[n][di + 128];
#pragma unroll
      for (int i = 0; i < 6; ++i) {
        acc[i][0] = fmaf(kc[i], vd0, acc[i][0]);
        acc[i][1] = fmaf(kc[i], vd1, acc[i][1]);
        acc[i][2] = fmaf(kc[i], vd2, acc[i][2]);
      }
    }
    __syncthreads();
  }
  float* outp = kvp + (size_t)ts * 1179648 + (size_t)b * 36864;
#pragma unroll
  for (int i = 0; i < 6; ++i)
#pragma unroll
    for (int u = 0; u < 3; ++u)
      outp[(c0 + ci * 6 + i) * 192 + di + 64 * u] = acc[i][u];
}

__global__ __launch_bounds__(256) void k3b_red(
    const float* __restrict__ kvp, ushort* __restrict__ kvT) {
  const int i = (blockIdx.x * 256 + threadIdx.x) * 2;
  const float s0 = kvp[i] + kvp[i + 1179648] + kvp[i + 2 * 1179648] + kvp[i + 3 * 1179648];
  const float s1 = kvp[i + 1] + kvp[i + 1 + 1179648] + kvp[i + 1 + 2 * 1179648] + kvp[i + 1 + 3 * 1179648];
  ushort2 o;
  o.x = f2bf(s0);
  o.y = f2bf(s1);
  *(ushort2*)&kvT[i] = o;
}

// ---------------------------------------------------------------------------
// K3c (MFMA): o1 = qs@KV; residual; LN; FFN; residual. Unchanged.
// ---------------------------------------------------------------------------
__global__ __launch_bounds__(256) void k3c_mfma(
    float* __restrict__ xb, const ushort* __restrict__ qs_bf,
    const ushort* __restrict__ kvT, const float* __restrict__ lnw,
    const float* __restrict__ lnb, const ushort* __restrict__ f1T,
    const ushort* __restrict__ f2T, const float* __restrict__ f1b,
    const float* __restrict__ f2b, const float* __restrict__ g1,
    const float* __restrict__ g2, int depth) {
  const int t = threadIdx.x;
  const int lane = t & 63, wid = t >> 6;
  const int wm = wid >> 1, wn = wid & 1;
  const int l15 = lane & 15, lg4 = lane >> 4;
  const int tok0 = blockIdx.x * 32;
  const int b = blockIdx.x >> 3;

  __shared__ __align__(16) char smem[12800 + 15360 + 12800 + 512];
  ushort (*s_a)[200] = (ushort(*)[200])smem;
  ushort (*s_w)[40] = (ushort(*)[40])(smem + 12800);
  ushort (*s_ff)[200] = (ushort(*)[200])(smem + 12800 + 15360);
  float (*s_red)[4] = (float(*)[4])(smem + 12800 + 15360 + 12800);

#pragma unroll
  for (int i = 0; i < 3; ++i) {
    const int idx = t + 256 * i;
    const int row = idx / 24, c8 = (idx % 24) * 8;
    *(uint4*)&s_a[row][c8] = *(const uint4*)&qs_bf[((size_t)tok0 + row) * 192 + c8];
  }
  __syncthreads();

  f32x4 o1[6];
#pragma unroll
  for (int f = 0; f < 6; ++f) o1[f] = (f32x4){0.f, 0.f, 0.f, 0.f};
  const ushort* kvb = kvT + (size_t)b * 36864;
#pragma unroll 1
  for (int ks = 0; ks < 6; ++ks) {
#pragma unroll
    for (int i = 0; i < 3; ++i) {
      const int idx = t + 256 * i;
      const int row = idx >> 2, c4 = (idx & 3) * 8;
      *(uint4*)&s_w[row][c4] = *(const uint4*)&kvb[row * 192 + ks * 32 + c4];
    }
    __syncthreads();
    const bf16x8 a = *(const bf16x8*)&s_a[wm * 16 + l15][ks * 32 + 8 * lg4];
#pragma unroll
    for (int f = 0; f < 6; ++f) {
      const bf16x8 bb = *(const bf16x8*)&s_w[wn * 96 + 16 * f + l15][8 * lg4];
      o1[f] = __builtin_amdgcn_mfma_f32_16x16x32_bf16(a, bb, o1[f], 0, 0, 0);
    }
    __syncthreads();
  }

  const float* g1p = g1 + depth * 192;
  const float* lw = lnw + depth * 192;
  const float* lb = lnb + depth * 192;
  const int rl = wm * 16 + 4 * lg4;
  float xbn[6][4];
  float psum[4] = {0.f, 0.f, 0.f, 0.f}, psq[4] = {0.f, 0.f, 0.f, 0.f};
#pragma unroll
  for (int f = 0; f < 6; ++f) {
    const int col = wn * 96 + 16 * f + l15;
#pragma unroll
    for (int reg = 0; reg < 4; ++reg) {
      const float xv =
          xb[((size_t)tok0 + rl + reg) * 192 + col] + o1[f][reg] * g1p[col];
      xbn[f][reg] = xv;
      psum[reg] += xv;
      psq[reg] = fmaf(xv, xv, psq[reg]);
    }
  }
#pragma unroll
  for (int reg = 0; reg < 4; ++reg) {
#pragma unroll
    for (int o = 8; o > 0; o >>= 1) {
      psum[reg] += __shfl_xor(psum[reg], o, 64);
      psq[reg] += __shfl_xor(psq[reg], o, 64);
    }
  }
  if (l15 == 0) {
#pragma unroll
    for (int reg = 0; reg < 4; ++reg) {
      s_red[rl + reg][wn] = psum[reg];
      s_red[rl + reg][2 + wn] = psq[reg];
    }
  }
  __syncthreads();
  float mean[4], inv[4];
#pragma unroll
  for (int reg = 0; reg < 4; ++reg) {
    const float s = s_red[rl + reg][0] + s_red[rl + reg][1];
    const float q = s_red[rl + reg][2] + s_red[rl + reg][3];
    mean[reg] = s * (1.f / 192.f);
    const float var = q * (1.f / 192.f) - mean[reg] * mean[reg];
    inv[reg] = rsqrtf(var + 1e-5f);
  }
#pragma unroll
  for (int f = 0; f < 6; ++f) {
    const int col = wn * 96 + 16 * f + l15;
#pragma unroll
    for (int reg = 0; reg < 4; ++reg)
      s_a[rl + reg][col] =
          f2bf((xbn[f][reg] - mean[reg]) * inv[reg] * lw[col] + lb[col]);
  }
  __syncthreads();

  f32x4 o2[6];
#pragma unroll
  for (int f = 0; f < 6; ++f) o2[f] = (f32x4){0.f, 0.f, 0.f, 0.f};
#pragma unroll 1
  for (int h = 0; h < 2; ++h) {
    f32x4 hh[6];
#pragma unroll
    for (int f = 0; f < 6; ++f) hh[f] = (f32x4){0.f, 0.f, 0.f, 0.f};
    const ushort* f1base = f1T + depth * 73728 + h * 36864;
#pragma unroll 1
    for (int ks = 0; ks < 6; ++ks) {
#pragma unroll
      for (int i = 0; i < 3; ++i) {
        const int idx = t + 256 * i;
        const int row = idx >> 2, c4 = (idx & 3) * 8;
        *(uint4*)&s_w[row][c4] = *(const uint4*)&f1base[row * 192 + ks * 32 + c4];
      }
      __syncthreads();
      const bf16x8 a = *(const bf16x8*)&s_a[wm * 16 + l15][ks * 32 + 8 * lg4];
#pragma unroll
      for (int f = 0; f < 6; ++f) {
        const bf16x8 bb = *(const bf16x8*)&s_w[wn * 96 + 16 * f + l15][8 * lg4];
        hh[f] = __builtin_amdgcn_mfma_f32_16x16x32_bf16(a, bb, hh[f], 0, 0, 0);
      }
      __syncthreads();
    }
    const float* b1p = f1b + depth * 384 + h * 192;
#pragma unroll
    for (int f = 0; f < 6; ++f) {
      const int col = wn * 96 + 16 * f + l15;
#pragma unroll
      for (int reg = 0; reg < 4; ++reg)
        s_ff[rl + reg][col] = f2bf(gelu_f(hh[f][reg] + b1p[col]));
    }
    __syncthreads();
    const ushort* f2base = f2T + depth * 73728;
#pragma unroll 1
    for (int ks2 = 0; ks2 < 6; ++ks2) {
#pragma unroll
      for (int i = 0; i < 3; ++i) {
        const int idx = t + 256 * i;
        const int row = idx >> 2, c4 = (idx & 3) * 8;
        *(uint4*)&s_w[row][c4] =
            *(const uint4*)&f2base[row * 384 + h * 192 + ks2 * 32 + c4];
      }
      __syncthreads();
      const bf16x8 a = *(const bf16x8*)&s_ff[wm * 16 + l15][ks2 * 32 + 8 * lg4];
#pragma unroll
      for (int f = 0; f < 6; ++f) {
        const bf16x8 bb = *(const bf16x8*)&s_w[wn * 96 + 16 * f + l15][8 * lg4];
        o2[f] = __builtin_amdgcn_mfma_f32_16x16x32_bf16(a, bb, o2[f], 0, 0, 0);
      }
      __syncthreads();
    }
  }

  const float* b2p = f2b + depth * 192;
  const float* g2p = g2 + depth * 192;
#pragma unroll
  for (int f = 0; f < 6; ++f) {
    const int col = wn * 96 + 16 * f + l15;
#pragma unroll
    for (int reg = 0; reg < 4; ++reg)
      xb[((size_t)tok0 + rl + reg) * 192 + col] =
          xbn[f][reg] + (o2[f][reg] + b2p[col]) * g2p[col];
  }
}

// ---------------------------------------------------------------------------
// K4: feat = LN(mean_n xb); out = feat @ head_w + head_b.
// ---------------------------------------------------------------------------
__global__ __launch_bounds__(192) void k4_head(
    const float* __restrict__ xb, const float* __restrict__ flnw,
    const float* __restrict__ flnb, const float* __restrict__ hw,
    const float* __restrict__ hb, float* __restrict__ out) {
  const int b = blockIdx.x, t = threadIdx.x;
  const int w = t >> 6, lane = t & 63;
  float s = 0.f;
  const float* base = xb + (size_t)b * 256 * 192 + t;
#pragma unroll 4
  for (int n = 0; n < 256; ++n) s += base[n * 192];
  const float feat_pre = s * (1.f / 256.f);
  __shared__ float red[3];
  __shared__ float feat[192];
  float sm = wsum64(feat_pre);
  if (lane == 0) red[w] = sm;
  __syncthreads();
  const float mean = (red[0] + red[1] + red[2]) * (1.f / 192.f);
  __syncthreads();
  const float dd = feat_pre - mean;
  sm = wsum64(dd * dd);
  if (lane == 0) red[w] = sm;
  __syncthreads();
  const float var = (red[0] + red[1] + red[2]) * (1.f / 192.f);
  feat[t] = dd * rsqrtf(var + 1e-5f) * flnw[t] + flnb[t];
  __syncthreads();
  if (t < 9) {
    float a = hb[t];
    for (int d = 0; d < 192; ++d) a = fmaf(feat[d], hw[d * 9 + t], a);
    out[b * 9 + t] = a;
  }
}

// ---------------------------------------------------------------------------
extern "C" void kernel_launch(void* const* d_in, const int* in_sizes, int n_in,
                              void* d_out, int out_size, void* d_ws, size_t ws_size,
                              hipStream_t stream) {
  (void)in_sizes; (void)n_in; (void)out_size; (void)ws_size;
  const float* x          = (const float*)d_in[0];
  const float* band_w     = (const float*)d_in[1];
  const float* band_b     = (const float*)d_in[2];
  const float* dw_w       = (const float*)d_in[3];
  const float* pw_w       = (const float*)d_in[4];
  const float* pe_ln_w    = (const float*)d_in[5];
  const float* pe_ln_b    = (const float*)d_in[6];
  const float* spec_proto = (const float*)d_in[7];
  const float* spat_proto = (const float*)d_in[8];
  const float* r1_w       = (const float*)d_in[9];
  const float* r1_b       = (const float*)d_in[10];
  const float* r2_w       = (const float*)d_in[11];
  const float* r2_b       = (const float*)d_in[12];
  const float* key_w      = (const float*)d_in[13];
  const float* pos_bias   = (const float*)d_in[14];
  const float* blk_ln_w   = (const float*)d_in[15];
  const float* blk_ln_b   = (const float*)d_in[16];
  const float* blk_q_w    = (const float*)d_in[17];
  const float* blk_v_w    = (const float*)d_in[18];
  const float* blk_f1_w   = (const float*)d_in[19];
  const float* blk_f1_b   = (const float*)d_in[20];
  const float* blk_f2_w   = (const float*)d_in[21];
  const float* blk_f2_b   = (const float*)d_in[22];
  const float* blk_g1     = (const float*)d_in[23];
  const float* blk_g2     = (const float*)d_in[24];
  const float* fin_ln_w   = (const float*)d_in[25];
  const float* fin_ln_b   = (const float*)d_in[26];
  const float* head_w     = (const float*)d_in[27];
  const float* head_b     = (const float*)d_in[28];

  float* ws   = (float*)d_ws;
  float* dw    = ws;                   //    65,536 f32
  float* xbuf  = dw + 65536;           // 1,572,864 f32
  float* keys  = xbuf + 1572864;       // 1,572,864 f32
  float* vbuf  = keys + 1572864;       // 1,572,864 f32
  float* kvp   = vbuf + 1572864;       // 4,718,592 f32
  float* bandT = kvp + 4718592;        //     1,024 f32 (824 used)
  ushort* ush   = (ushort*)(bandT + 1024);
  ushort* qs_bf = ush;                 // 1,572,864
  ushort* kvT   = qs_bf + 1572864;     // 1,179,648
  ushort* qwT   = kvT + 1179648;       //   110,592
  ushort* vwT   = qwT + 110592;        //   110,592
  ushort* f1T   = vwT + 110592;        //   221,184
  ushort* f2T   = f1T + 221184;        //   221,184
  ushort* r1T   = f2T + 221184;        //    24,576
  ushort* r2T   = r1T + 24576;         //     6,144
  ushort* keyT  = r2T + 6144;          //    43,008

  prep_w<<<864, 256, 0, stream>>>(blk_q_w, blk_v_w, blk_f1_w, blk_f2_w,
                                  r1_w, r2_w, key_w, band_w,
                                  qwT, vwT, f1T, f2T, r1T, r2T, keyT, bandT);
  k1_band_dw<<<512, 512, 0, stream>>>(x, bandT, band_b, dw_w, dw);
  k2_mfma<<<256, 256, 0, stream>>>(dw, pw_w, pe_ln_w, pe_ln_b, spec_proto,
                                   spat_proto, r1T, r1_b, r2T, r2_b, keyT,
                                   pos_bias, xbuf, keys);
  for (int d = 0; d < 3; ++d) {
    k3a_mfma<<<256, 256, 0, stream>>>(xbuf, blk_ln_w, blk_ln_b, qwT, vwT,
                                      qs_bf, vbuf, d);
    k3b_kv<<<1024, 256, 0, stream>>>(vbuf, keys, kvp);
    k3b_red<<<2304, 256, 0, stream>>>(kvp, kvT);
    k3c_mfma<<<256, 256, 0, stream>>>(xbuf, qs_bf, kvT, blk_ln_w, blk_ln_b,
                                      f1T, f2T, blk_f1_b, blk_f2_b, blk_g1,
                                      blk_g2, d);
  }
  k4_head<<<32, 192, 0, stream>>>(xbuf, fin_ln_w, fin_ln_b, head_w, head_b,
                                  (float*)d_out);
}

// Round 6
// 333.168 us; speedup vs baseline: 2.4282x; 1.2214x over previous
//
#include <hip/hip_runtime.h>
#include <math.h>

// ---------------------------------------------------------------------------
// OptimizedProtoHyperFormer — round 6: round-5 plan with fixed nontemporal
// loads (clang ext-vector type instead of HIP float4).
// B=32, IB=103, H=W=256, P=16, RB=8, DIM=192, DEPTH=3, FFH=384, NT=8192.
// ---------------------------------------------------------------------------

typedef __attribute__((ext_vector_type(8))) short bf16x8;
typedef __attribute__((ext_vector_type(4))) float f32x4;

__device__ __forceinline__ float wsum64(float v) {
#pragma unroll
  for (int o = 32; o > 0; o >>= 1) v += __shfl_xor(v, o, 64);
  return v;
}
__device__ __forceinline__ float sum16(float v) {
#pragma unroll
  for (int o = 8; o > 0; o >>= 1) v += __shfl_xor(v, o, 64);
  return v;
}
__device__ __forceinline__ float max16(float v) {
#pragma unroll
  for (int o = 8; o > 0; o >>= 1) v = fmaxf(v, __shfl_xor(v, o, 64));
  return v;
}
__device__ __forceinline__ float gelu_f(float x) {
  return 0.5f * x * (1.0f + erff(x * 0.7071067811865476f));
}
__device__ __forceinline__ ushort f2bf(float f) {
  union { float f; unsigned u; } v;
  v.f = f;
  unsigned r = v.u + 0x7FFFu + ((v.u >> 16) & 1u);
  return (ushort)(r >> 16);
}

// ---------------------------------------------------------------------------
// prep: bf16 transposes of all MFMA weights + band_w transpose.
// ---------------------------------------------------------------------------
__global__ __launch_bounds__(256) void prep_w(
    const float* __restrict__ qw, const float* __restrict__ vw,
    const float* __restrict__ f1w, const float* __restrict__ f2w,
    const float* __restrict__ r1_w, const float* __restrict__ r2_w,
    const float* __restrict__ key_w, const float* __restrict__ band_w,
    ushort* __restrict__ qwT, ushort* __restrict__ vwT,
    ushort* __restrict__ f1T, ushort* __restrict__ f2T,
    ushort* __restrict__ r1T, ushort* __restrict__ r2T,
    ushort* __restrict__ keyT, float* __restrict__ bandT) {
  const int i = blockIdx.x * 256 + threadIdx.x;
  if (i < 110592) {  // qw, vw: [3][192][192] -> [3][j][k]
    const int d = i / 36864, r = i % 36864;
    const int k = r / 192, c = r % 192;
    qwT[d * 36864 + c * 192 + k] = f2bf(qw[i]);
    vwT[d * 36864 + c * 192 + k] = f2bf(vw[i]);
  }
  if (i < 221184) {
    const int d = i / 73728, r = i % 73728;
    const int k = r / 384, j = r % 384;        // f1: [3][192][384] -> [3][384][192]
    f1T[d * 73728 + j * 192 + k] = f2bf(f1w[i]);
    const int k2 = r / 192, j2 = r % 192;      // f2: [3][384][192] -> [3][192][384]
    f2T[d * 73728 + j2 * 384 + k2] = f2bf(f2w[i]);
  }
  if (i < 24576) {  // r1: [192][128] -> [j:128][k:192]
    const int j = i / 192, k = i % 192;
    r1T[i] = f2bf(r1_w[k * 128 + j]);
  }
  if (i < 6144) {   // r2: [128][48] -> [j:48][k:128]
    const int j = i / 128, k = i % 128;
    r2T[i] = f2bf(r2_w[k * 48 + j]);
  }
  if (i < 43008) {  // key: [200][192] -> [j:192][k:224 padded]
    const int j = i / 224, k = i % 224;
    keyT[i] = (k < 200) ? f2bf(key_w[k * 192 + j]) : (ushort)0;
  }
  if (i < 824) {    // band_w: [8][103] -> [103][8]
    const int ch = i >> 3, c = i & 7;
    bandT[i] = band_w[c * 103 + ch];
  }
}

// ---------------------------------------------------------------------------
// K1: fused band-reduction (103->8) + depthwise patch conv.
// 512 blocks (batch x patch-row), 512 threads, nontemporal streamed loads.
// ---------------------------------------------------------------------------
__global__ __launch_bounds__(512) void k1_band_dw(
    const float* __restrict__ x, const float* __restrict__ bandT,
    const float* __restrict__ band_b, const float* __restrict__ dw_w,
    float* __restrict__ dw_out) {
  const int blk = blockIdx.x;
  const int b = blk >> 4, ip = blk & 15;
  const int t = threadIdx.x;
  const int col4 = t & 63;
  const int j = col4 >> 2;
  const int qb = (col4 & 3) << 2;
  const int p0 = t >> 6;

  float acc[8][8];
#pragma unroll
  for (int e = 0; e < 8; ++e)
#pragma unroll
    for (int c = 0; c < 8; ++c) acc[e][c] = 0.f;

  const f32x4* xp = (const f32x4*)x + (size_t)b * (103 * 16384) + (size_t)ip * 1024;

  auto body = [&](const f32x4 v0, const f32x4 v1, const int ch) {
    const f32x4 wA = *(const f32x4*)&bandT[ch * 8];
    const f32x4 wB = *(const f32x4*)&bandT[ch * 8 + 4];
    const float bw[8] = {wA.x, wA.y, wA.z, wA.w, wB.x, wB.y, wB.z, wB.w};
#pragma unroll
    for (int c = 0; c < 8; ++c) {
      acc[0][c] = fmaf(v0.x, bw[c], acc[0][c]);
      acc[1][c] = fmaf(v0.y, bw[c], acc[1][c]);
      acc[2][c] = fmaf(v0.z, bw[c], acc[2][c]);
      acc[3][c] = fmaf(v0.w, bw[c], acc[3][c]);
      acc[4][c] = fmaf(v1.x, bw[c], acc[4][c]);
      acc[5][c] = fmaf(v1.y, bw[c], acc[5][c]);
      acc[6][c] = fmaf(v1.z, bw[c], acc[6][c]);
      acc[7][c] = fmaf(v1.w, bw[c], acc[7][c]);
    }
  };

  f32x4 p0v = __builtin_nontemporal_load(&xp[t]);
  f32x4 p1v = __builtin_nontemporal_load(&xp[t + 512]);
  f32x4 q0v = __builtin_nontemporal_load(&xp[t + 16384]);
  f32x4 q1v = __builtin_nontemporal_load(&xp[t + 16896]);
#pragma unroll 1
  for (int ch = 0; ch < 100; ch += 2) {
    const f32x4 r0 = __builtin_nontemporal_load(&xp[t + 2 * 16384]);
    const f32x4 r1 = __builtin_nontemporal_load(&xp[t + 2 * 16384 + 512]);
    const f32x4 s0 = __builtin_nontemporal_load(&xp[t + 3 * 16384]);
    const f32x4 s1 = __builtin_nontemporal_load(&xp[t + 3 * 16384 + 512]);
    body(p0v, p1v, ch);
    body(q0v, q1v, ch + 1);
    p0v = r0; p1v = r1; q0v = s0; q1v = s1;
    xp += 2 * 16384;
  }
  const f32x4 u0 = __builtin_nontemporal_load(&xp[t + 2 * 16384]);
  const f32x4 u1 = __builtin_nontemporal_load(&xp[t + 2 * 16384 + 512]);
  body(p0v, p1v, 100);
  body(q0v, q1v, 101);
  body(u0, u1, 102);

  float dwt[8];
#pragma unroll
  for (int c = 0; c < 8; ++c) dwt[c] = 0.f;
#pragma unroll
  for (int e = 0; e < 8; ++e) {
    const int pp = p0 + ((e >> 2) << 3);
    const int qq = qb + (e & 3);
#pragma unroll
    for (int c = 0; c < 8; ++c)
      dwt[c] = fmaf(dw_w[c * 256 + pp * 16 + qq], acc[e][c] + band_b[c], dwt[c]);
  }
#pragma unroll
  for (int c = 0; c < 8; ++c) {
    dwt[c] += __shfl_xor(dwt[c], 1, 64);
    dwt[c] += __shfl_xor(dwt[c], 2, 64);
  }
  __shared__ float part[8][16][8];
  if ((t & 3) == 0) {
#pragma unroll
    for (int c = 0; c < 8; ++c) part[t >> 6][j][c] = dwt[c];
  }
  __syncthreads();
  if (t < 128) {
    const int jj = t >> 3, c = t & 7;
    float s = 0.f;
#pragma unroll
    for (int w = 0; w < 8; ++w) s += part[w][jj][c];
    dw_out[(((size_t)b * 16 + ip) * 16 + jj) * 8 + c] = s;
  }
}

// ---------------------------------------------------------------------------
// K2 (MFMA): pw+LN -> router r1/r2 -> top2 -> proto mix -> keysT bf16.
// 32 tokens/block, 256 blocks, 4 waves.
// ---------------------------------------------------------------------------
__global__ __launch_bounds__(256) void k2_mfma(
    const float* __restrict__ dw, const float* __restrict__ pw_w,
    const float* __restrict__ pe_ln_w, const float* __restrict__ pe_ln_b,
    const float* __restrict__ spec_proto, const float* __restrict__ spat_proto,
    const ushort* __restrict__ r1T, const float* __restrict__ r1_b,
    const ushort* __restrict__ r2T, const float* __restrict__ r2_b,
    const ushort* __restrict__ keyT, const float* __restrict__ pos_bias,
    float* __restrict__ xb_out, ushort* __restrict__ keysT) {
  const int t = threadIdx.x;
  const int lane = t & 63, wid = t >> 6;
  const int wm = wid >> 1, wn = wid & 1;
  const int l15 = lane & 15, lg4 = lane >> 4;
  const int tok0 = blockIdx.x * 32;
  const int rl = wm * 16 + 4 * lg4;
  const int b = blockIdx.x >> 3;
  const int n0 = (blockIdx.x & 7) * 32;

  __shared__ float dw8s[32][8];
  __shared__ __align__(16) ushort s_xn[32][200];
  __shared__ __align__(16) ushort s_w[192][40];
  __shared__ __align__(16) ushort s_h[32][200];
  __shared__ __align__(16) ushort s_mix[32][232];
  __shared__ float s_rl[32][48];
  __shared__ float topwS[32][4];
  __shared__ int   topiS[32][4];

  dw8s[t >> 3][t & 7] = dw[((size_t)tok0 + (t >> 3)) * 8 + (t & 7)];
  __syncthreads();

  // ---- phase 1: pw + LN -> xb fp32, s_xn bf16 ----
#pragma unroll
  for (int half = 0; half < 2; ++half) {
    const int tt = half * 16 + (t >> 4), lg = t & 15;
    float pre[12], sm = 0.f;
#pragma unroll
    for (int m = 0; m < 12; ++m) {
      const int d = lg + 16 * m;
      const f32x4 pa = *(const f32x4*)&pw_w[d * 8];
      const f32x4 pb = *(const f32x4*)&pw_w[d * 8 + 4];
      float p = pa.x * dw8s[tt][0] + pa.y * dw8s[tt][1] + pa.z * dw8s[tt][2] +
                pa.w * dw8s[tt][3] + pb.x * dw8s[tt][4] + pb.y * dw8s[tt][5] +
                pb.z * dw8s[tt][6] + pb.w * dw8s[tt][7];
      pre[m] = p;
      sm += p;
    }
    sm = sum16(sm);
    const float mean = sm * (1.f / 192.f);
    float vv = 0.f;
#pragma unroll
    for (int m = 0; m < 12; ++m) {
      const float d0 = pre[m] - mean;
      vv = fmaf(d0, d0, vv);
    }
    vv = sum16(vv);
    const float inv = rsqrtf(vv * (1.f / 192.f) + 1e-5f);
#pragma unroll
    for (int m = 0; m < 12; ++m) {
      const int d = lg + 16 * m;
      const float xv = (pre[m] - mean) * inv * pe_ln_w[d] + pe_ln_b[d];
      s_xn[tt][d] = f2bf(xv);
      xb_out[((size_t)tok0 + tt) * 192 + d] = xv;
    }
  }
  __syncthreads();

  // ---- phase 2: r1 (K=192 -> 128) + gelu -> s_h bf16 ----
  {
    f32x4 hacc[4];
#pragma unroll
    for (int f = 0; f < 4; ++f) hacc[f] = (f32x4){0.f, 0.f, 0.f, 0.f};
#pragma unroll 1
    for (int ks = 0; ks < 6; ++ks) {
#pragma unroll
      for (int i = 0; i < 2; ++i) {
        const int lin = t + 256 * i;
        const int row = lin >> 2, c8 = (lin & 3) * 8;
        *(uint4*)&s_w[row][c8] = *(const uint4*)&r1T[row * 192 + ks * 32 + c8];
      }
      __syncthreads();
      const bf16x8 a = *(const bf16x8*)&s_xn[wm * 16 + l15][ks * 32 + 8 * lg4];
#pragma unroll
      for (int f = 0; f < 4; ++f) {
        const bf16x8 bb = *(const bf16x8*)&s_w[wn * 64 + 16 * f + l15][8 * lg4];
        hacc[f] = __builtin_amdgcn_mfma_f32_16x16x32_bf16(a, bb, hacc[f], 0, 0, 0);
      }
      __syncthreads();
    }
#pragma unroll
    for (int f = 0; f < 4; ++f) {
      const int col = wn * 64 + 16 * f + l15;
#pragma unroll
      for (int reg = 0; reg < 4; ++reg)
        s_h[rl + reg][col] = f2bf(gelu_f(hacc[f][reg] + r1_b[col]));
    }
  }
  __syncthreads();

  // ---- phase 3: r2 (K=128 -> 48) -> s_rl fp32 ----
  {
    f32x4 racc[2];
    racc[0] = (f32x4){0.f, 0.f, 0.f, 0.f};
    racc[1] = (f32x4){0.f, 0.f, 0.f, 0.f};
#pragma unroll 1
    for (int ks = 0; ks < 4; ++ks) {
      if (t < 192) {
        const int row = t >> 2, c8 = (t & 3) * 8;
        *(uint4*)&s_w[row][c8] = *(const uint4*)&r2T[row * 128 + ks * 32 + c8];
      }
      __syncthreads();
      const bf16x8 a = *(const bf16x8*)&s_h[wm * 16 + l15][ks * 32 + 8 * lg4];
      if (wn == 0) {
#pragma unroll
        for (int f = 0; f < 2; ++f) {
          const bf16x8 bb = *(const bf16x8*)&s_w[16 * f + l15][8 * lg4];
          racc[f] = __builtin_amdgcn_mfma_f32_16x16x32_bf16(a, bb, racc[f], 0, 0, 0);
        }
      } else {
        const bf16x8 bb = *(const bf16x8*)&s_w[32 + l15][8 * lg4];
        racc[0] = __builtin_amdgcn_mfma_f32_16x16x32_bf16(a, bb, racc[0], 0, 0, 0);
      }
      __syncthreads();
    }
    if (wn == 0) {
#pragma unroll
      for (int f = 0; f < 2; ++f) {
        const int col = 16 * f + l15;
#pragma unroll
        for (int reg = 0; reg < 4; ++reg)
          s_rl[rl + reg][col] = racc[f][reg] + r2_b[col];
      }
    } else {
      const int col = 32 + l15;
#pragma unroll
      for (int reg = 0; reg < 4; ++reg)
        s_rl[rl + reg][col] = racc[0][reg] + r2_b[col];
    }
  }
  __syncthreads();

  // ---- phase 4: top-2 + tau softmax (fp32) ----
  if (t < 64) {
    const int tt = t >> 1, half = t & 1;
    const float* base = &s_rl[tt][half * 24];
    float v0 = -1e30f, v1 = -1e30f;
    int i0 = 0, i1 = 0;
    for (int k = 0; k < 24; ++k) {
      const float vv = base[k];
      if (vv > v0) { v1 = v0; i1 = i0; v0 = vv; i0 = k; }
      else if (vv > v1) { v1 = vv; i1 = k; }
    }
    const float tau = (float)(0.07 + 1e-8);
    const float e1 = expf((v1 - v0) / tau);
    const float inv = 1.f / (1.f + e1);
    topwS[tt][half * 2] = inv;
    topwS[tt][half * 2 + 1] = e1 * inv;
    topiS[tt][half * 2] = i0;
    topiS[tt][half * 2 + 1] = i1;
  }
  __syncthreads();

  // ---- phase 5: mixed prototypes s_mix[32][224 padded] bf16 ----
#pragma unroll
  for (int r = 0; r < 28; ++r) {
    const int f = t + 256 * r;  // 32*224 = 7168 exact
    const int tok = f / 224, c = f % 224;
    float val = 0.f;
    if (c < 8) {
      val = topwS[tok][0] * spec_proto[topiS[tok][0] * 8 + c] +
            topwS[tok][1] * spec_proto[topiS[tok][1] * 8 + c];
    } else if (c < 200) {
      const int cc = c - 8;
      val = topwS[tok][2] * spat_proto[topiS[tok][2] * 192 + cc] +
            topwS[tok][3] * spat_proto[topiS[tok][3] * 192 + cc];
    }
    s_mix[tok][c] = f2bf(val);
  }
  __syncthreads();

  // ---- phase 6: keys (K=224 -> 192) + pos_bias -> keysT[b][c][n] bf16 ----
  {
    f32x4 kacc[6];
#pragma unroll
    for (int f = 0; f < 6; ++f) kacc[f] = (f32x4){0.f, 0.f, 0.f, 0.f};
#pragma unroll 1
    for (int ks = 0; ks < 7; ++ks) {
#pragma unroll
      for (int i = 0; i < 3; ++i) {
        const int lin = t + 256 * i;
        const int row = lin >> 2, c8 = (lin & 3) * 8;
        *(uint4*)&s_w[row][c8] = *(const uint4*)&keyT[row * 224 + ks * 32 + c8];
      }
      __syncthreads();
      const bf16x8 a = *(const bf16x8*)&s_mix[wm * 16 + l15][ks * 32 + 8 * lg4];
#pragma unroll
      for (int f = 0; f < 6; ++f) {
        const bf16x8 bb = *(const bf16x8*)&s_w[wn * 96 + 16 * f + l15][8 * lg4];
        kacc[f] = __builtin_amdgcn_mfma_f32_16x16x32_bf16(a, bb, kacc[f], 0, 0, 0);
      }
      __syncthreads();
    }
#pragma unroll
    for (int f = 0; f < 6; ++f) {
      const int col = wn * 96 + 16 * f + l15;
#pragma unroll
      for (int reg = 0; reg < 4; ++reg)
        keysT[((size_t)b * 192 + col) * 256 + n0 + rl + reg] =
            f2bf(kacc[f][reg] + pos_bias[col]);
    }
  }
}

// ---------------------------------------------------------------------------
// K3a (MFMA): LN -> xn bf16; q,v; softmax(q) -> qs bf16; v -> vT[b][d][n] bf16.
// ---------------------------------------------------------------------------
__global__ __launch_bounds__(256) void k3a_mfma(
    const float* __restrict__ xb, const float* __restrict__ lnw,
    const float* __restrict__ lnb, const ushort* __restrict__ qwT,
    const ushort* __restrict__ vwT, ushort* __restrict__ qs_bf,
    ushort* __restrict__ vT, int depth) {
  const int t = threadIdx.x;
  const int lane = t & 63, wid = t >> 6;
  const int wm = wid >> 1, wn = wid & 1;
  const int l15 = lane & 15, lg4 = lane >> 4;
  const int tok0 = blockIdx.x * 32;
  const int b = blockIdx.x >> 3;
  const int n0 = (blockIdx.x & 7) * 32;

  __shared__ __align__(16) char smem[12800 + 30720];
  ushort (*s_xn)[200] = (ushort(*)[200])smem;
  ushort (*s_wq)[40] = (ushort(*)[40])(smem + 12800);
  ushort (*s_wv)[40] = (ushort(*)[40])(smem + 12800 + 15360);
  float (*s_q)[196] = (float(*)[196])(smem + 12800);

  const float* lw = lnw + depth * 192;
  const float* lb = lnb + depth * 192;
#pragma unroll
  for (int half = 0; half < 2; ++half) {
    const int tt = half * 16 + (t >> 4);
    const int lg = t & 15;
    const float* xrow = xb + ((size_t)tok0 + tt) * 192;
    float vals[12], sm = 0.f;
#pragma unroll
    for (int m = 0; m < 12; ++m) {
      vals[m] = xrow[lg + 16 * m];
      sm += vals[m];
    }
    sm = sum16(sm);
    const float mean = sm * (1.f / 192.f);
    float vv = 0.f;
#pragma unroll
    for (int m = 0; m < 12; ++m) {
      const float d0 = vals[m] - mean;
      vv = fmaf(d0, d0, vv);
    }
    vv = sum16(vv);
    const float inv = rsqrtf(vv * (1.f / 192.f) + 1e-5f);
#pragma unroll
    for (int m = 0; m < 12; ++m) {
      const int d = lg + 16 * m;
      s_xn[tt][d] = f2bf((vals[m] - mean) * inv * lw[d] + lb[d]);
    }
  }
  __syncthreads();

  f32x4 aq[6], av[6];
#pragma unroll
  for (int f = 0; f < 6; ++f) {
    aq[f] = (f32x4){0.f, 0.f, 0.f, 0.f};
    av[f] = (f32x4){0.f, 0.f, 0.f, 0.f};
  }
  const ushort* qbase = qwT + depth * 36864;
  const ushort* vbase = vwT + depth * 36864;
#pragma unroll 1
  for (int ks = 0; ks < 6; ++ks) {
#pragma unroll
    for (int i = 0; i < 3; ++i) {
      const int idx = t + 256 * i;
      const int row = idx >> 2, c4 = (idx & 3) * 8;
      *(uint4*)&s_wq[row][c4] = *(const uint4*)&qbase[row * 192 + ks * 32 + c4];
      *(uint4*)&s_wv[row][c4] = *(const uint4*)&vbase[row * 192 + ks * 32 + c4];
    }
    __syncthreads();
    const bf16x8 a = *(const bf16x8*)&s_xn[wm * 16 + l15][ks * 32 + 8 * lg4];
#pragma unroll
    for (int f = 0; f < 6; ++f) {
      const bf16x8 bq = *(const bf16x8*)&s_wq[wn * 96 + 16 * f + l15][8 * lg4];
      const bf16x8 bv = *(const bf16x8*)&s_wv[wn * 96 + 16 * f + l15][8 * lg4];
      aq[f] = __builtin_amdgcn_mfma_f32_16x16x32_bf16(a, bq, aq[f], 0, 0, 0);
      av[f] = __builtin_amdgcn_mfma_f32_16x16x32_bf16(a, bv, av[f], 0, 0, 0);
    }
    __syncthreads();
  }

  const int rl = wm * 16 + 4 * lg4;
#pragma unroll
  for (int f = 0; f < 6; ++f) {
    const int col = wn * 96 + 16 * f + l15;
#pragma unroll
    for (int reg = 0; reg < 4; ++reg) {
      vT[((size_t)b * 192 + col) * 256 + n0 + rl + reg] = f2bf(av[f][reg]);
      s_q[rl + reg][col] = aq[f][reg];
    }
  }
  __syncthreads();

#pragma unroll
  for (int half = 0; half < 2; ++half) {
    const int tt = half * 16 + (t >> 4);
    const int lg = t & 15;
    float vals[12], mx = -1e30f;
#pragma unroll
    for (int m = 0; m < 12; ++m) {
      vals[m] = s_q[tt][lg + 16 * m];
      mx = fmaxf(mx, vals[m]);
    }
    mx = max16(mx);
    float s = 0.f;
#pragma unroll
    for (int m = 0; m < 12; ++m) {
      vals[m] = expf(vals[m] - mx);
      s += vals[m];
    }
    s = sum16(s);
    const float inv = 1.f / s;
#pragma unroll
    for (int m = 0; m < 12; ++m)
      qs_bf[((size_t)tok0 + tt) * 192 + lg + 16 * m] = f2bf(vals[m] * inv);
  }
}

// ---------------------------------------------------------------------------
// K3b (MFMA): KV^T[b][d][c] = sum_n vT[b][d][n] * keysT[b][c][n], K=256.
// Grid: 32 batches x 6 d-tiles = 192 blocks, 4 waves, output kvT bf16.
// ---------------------------------------------------------------------------
__global__ __launch_bounds__(256) void k3b_mfma(
    const ushort* __restrict__ vT, const ushort* __restrict__ keysT,
    ushort* __restrict__ kvT) {
  const int t = threadIdx.x;
  const int lane = t & 63, wid = t >> 6;
  const int wm = wid >> 1, wn = wid & 1;
  const int l15 = lane & 15, lg4 = lane >> 4;
  const int b = blockIdx.x / 6;
  const int d0 = (blockIdx.x % 6) * 32;

  __shared__ __align__(16) ushort s_a[32][264];  // vT tile: 32 d-rows x 256 n
  __shared__ __align__(16) ushort s_w[192][40];  // keysT stage: 192 c x 32 n

  const ushort* vbase = vT + ((size_t)b * 192 + d0) * 256;
#pragma unroll
  for (int i = 0; i < 4; ++i) {
    const int idx = t + 256 * i;
    const int row = idx >> 5, c8 = (idx & 31) * 8;
    *(uint4*)&s_a[row][c8] = *(const uint4*)&vbase[row * 256 + c8];
  }

  f32x4 acc[6];
#pragma unroll
  for (int f = 0; f < 6; ++f) acc[f] = (f32x4){0.f, 0.f, 0.f, 0.f};
  const ushort* kbase = keysT + (size_t)b * 192 * 256;
#pragma unroll 1
  for (int ks = 0; ks < 8; ++ks) {
#pragma unroll
    for (int i = 0; i < 3; ++i) {
      const int idx = t + 256 * i;
      const int row = idx >> 2, c4 = (idx & 3) * 8;
      *(uint4*)&s_w[row][c4] = *(const uint4*)&kbase[row * 256 + ks * 32 + c4];
    }
    __syncthreads();
    const bf16x8 a = *(const bf16x8*)&s_a[wm * 16 + l15][ks * 32 + 8 * lg4];
#pragma unroll
    for (int f = 0; f < 6; ++f) {
      const bf16x8 bb = *(const bf16x8*)&s_w[wn * 96 + 16 * f + l15][8 * lg4];
      acc[f] = __builtin_amdgcn_mfma_f32_16x16x32_bf16(a, bb, acc[f], 0, 0, 0);
    }
    __syncthreads();
  }

  const int rl = wm * 16 + 4 * lg4;
#pragma unroll
  for (int f = 0; f < 6; ++f) {
    const int col = wn * 96 + 16 * f + l15;
#pragma unroll
    for (int reg = 0; reg < 4; ++reg)
      kvT[((size_t)b * 192 + d0 + rl + reg) * 192 + col] = f2bf(acc[f][reg]);
  }
}

// ---------------------------------------------------------------------------
// K3c (MFMA): o1 = qs@KV; residual; LN; FFN; residual.
// ---------------------------------------------------------------------------
__global__ __launch_bounds__(256) void k3c_mfma(
    float* __restrict__ xb, const ushort* __restrict__ qs_bf,
    const ushort* __restrict__ kvT, const float* __restrict__ lnw,
    const float* __restrict__ lnb, const ushort* __restrict__ f1T,
    const ushort* __restrict__ f2T, const float* __restrict__ f1b,
    const float* __restrict__ f2b, const float* __restrict__ g1,
    const float* __restrict__ g2, int depth) {
  const int t = threadIdx.x;
  const int lane = t & 63, wid = t >> 6;
  const int wm = wid >> 1, wn = wid & 1;
  const int l15 = lane & 15, lg4 = lane >> 4;
  const int tok0 = blockIdx.x * 32;
  const int b = blockIdx.x >> 3;

  __shared__ __align__(16) char smem[12800 + 15360 + 12800 + 512];
  ushort (*s_a)[200] = (ushort(*)[200])smem;
  ushort (*s_w)[40] = (ushort(*)[40])(smem + 12800);
  ushort (*s_ff)[200] = (ushort(*)[200])(smem + 12800 + 15360);
  float (*s_red)[4] = (float(*)[4])(smem + 12800 + 15360 + 12800);

#pragma unroll
  for (int i = 0; i < 3; ++i) {
    const int idx = t + 256 * i;
    const int row = idx / 24, c8 = (idx % 24) * 8;
    *(uint4*)&s_a[row][c8] = *(const uint4*)&qs_bf[((size_t)tok0 + row) * 192 + c8];
  }
  __syncthreads();

  f32x4 o1[6];
#pragma unroll
  for (int f = 0; f < 6; ++f) o1[f] = (f32x4){0.f, 0.f, 0.f, 0.f};
  const ushort* kvb = kvT + (size_t)b * 36864;
#pragma unroll 1
  for (int ks = 0; ks < 6; ++ks) {
#pragma unroll
    for (int i = 0; i < 3; ++i) {
      const int idx = t + 256 * i;
      const int row = idx >> 2, c4 = (idx & 3) * 8;
      *(uint4*)&s_w[row][c4] = *(const uint4*)&kvb[row * 192 + ks * 32 + c4];
    }
    __syncthreads();
    const bf16x8 a = *(const bf16x8*)&s_a[wm * 16 + l15][ks * 32 + 8 * lg4];
#pragma unroll
    for (int f = 0; f < 6; ++f) {
      const bf16x8 bb = *(const bf16x8*)&s_w[wn * 96 + 16 * f + l15][8 * lg4];
      o1[f] = __builtin_amdgcn_mfma_f32_16x16x32_bf16(a, bb, o1[f], 0, 0, 0);
    }
    __syncthreads();
  }

  const float* g1p = g1 + depth * 192;
  const float* lw = lnw + depth * 192;
  const float* lb = lnb + depth * 192;
  const int rl = wm * 16 + 4 * lg4;
  float xbn[6][4];
  float psum[4] = {0.f, 0.f, 0.f, 0.f}, psq[4] = {0.f, 0.f, 0.f, 0.f};
#pragma unroll
  for (int f = 0; f < 6; ++f) {
    const int col = wn * 96 + 16 * f + l15;
#pragma unroll
    for (int reg = 0; reg < 4; ++reg) {
      const float xv =
          xb[((size_t)tok0 + rl + reg) * 192 + col] + o1[f][reg] * g1p[col];
      xbn[f][reg] = xv;
      psum[reg] += xv;
      psq[reg] = fmaf(xv, xv, psq[reg]);
    }
  }
#pragma unroll
  for (int reg = 0; reg < 4; ++reg) {
#pragma unroll
    for (int o = 8; o > 0; o >>= 1) {
      psum[reg] += __shfl_xor(psum[reg], o, 64);
      psq[reg] += __shfl_xor(psq[reg], o, 64);
    }
  }
  if (l15 == 0) {
#pragma unroll
    for (int reg = 0; reg < 4; ++reg) {
      s_red[rl + reg][wn] = psum[reg];
      s_red[rl + reg][2 + wn] = psq[reg];
    }
  }
  __syncthreads();
  float mean[4], inv[4];
#pragma unroll
  for (int reg = 0; reg < 4; ++reg) {
    const float s = s_red[rl + reg][0] + s_red[rl + reg][1];
    const float q = s_red[rl + reg][2] + s_red[rl + reg][3];
    mean[reg] = s * (1.f / 192.f);
    const float var = q * (1.f / 192.f) - mean[reg] * mean[reg];
    inv[reg] = rsqrtf(var + 1e-5f);
  }
#pragma unroll
  for (int f = 0; f < 6; ++f) {
    const int col = wn * 96 + 16 * f + l15;
#pragma unroll
    for (int reg = 0; reg < 4; ++reg)
      s_a[rl + reg][col] =
          f2bf((xbn[f][reg] - mean[reg]) * inv[reg] * lw[col] + lb[col]);
  }
  __syncthreads();

  f32x4 o2[6];
#pragma unroll
  for (int f = 0; f < 6; ++f) o2[f] = (f32x4){0.f, 0.f, 0.f, 0.f};
#pragma unroll 1
  for (int h = 0; h < 2; ++h) {
    f32x4 hh[6];
#pragma unroll
    for (int f = 0; f < 6; ++f) hh[f] = (f32x4){0.f, 0.f, 0.f, 0.f};
    const ushort* f1base = f1T + depth * 73728 + h * 36864;
#pragma unroll 1
    for (int ks = 0; ks < 6; ++ks) {
#pragma unroll
      for (int i = 0; i < 3; ++i) {
        const int idx = t + 256 * i;
        const int row = idx >> 2, c4 = (idx & 3) * 8;
        *(uint4*)&s_w[row][c4] = *(const uint4*)&f1base[row * 192 + ks * 32 + c4];
      }
      __syncthreads();
      const bf16x8 a = *(const bf16x8*)&s_a[wm * 16 + l15][ks * 32 + 8 * lg4];
#pragma unroll
      for (int f = 0; f < 6; ++f) {
        const bf16x8 bb = *(const bf16x8*)&s_w[wn * 96 + 16 * f + l15][8 * lg4];
        hh[f] = __builtin_amdgcn_mfma_f32_16x16x32_bf16(a, bb, hh[f], 0, 0, 0);
      }
      __syncthreads();
    }
    const float* b1p = f1b + depth * 384 + h * 192;
#pragma unroll
    for (int f = 0; f < 6; ++f) {
      const int col = wn * 96 + 16 * f + l15;
#pragma unroll
      for (int reg = 0; reg < 4; ++reg)
        s_ff[rl + reg][col] = f2bf(gelu_f(hh[f][reg] + b1p[col]));
    }
    __syncthreads();
    const ushort* f2base = f2T + depth * 73728;
#pragma unroll 1
    for (int ks2 = 0; ks2 < 6; ++ks2) {
#pragma unroll
      for (int i = 0; i < 3; ++i) {
        const int idx = t + 256 * i;
        const int row = idx >> 2, c4 = (idx & 3) * 8;
        *(uint4*)&s_w[row][c4] =
            *(const uint4*)&f2base[row * 384 + h * 192 + ks2 * 32 + c4];
      }
      __syncthreads();
      const bf16x8 a = *(const bf16x8*)&s_ff[wm * 16 + l15][ks2 * 32 + 8 * lg4];
#pragma unroll
      for (int f = 0; f < 6; ++f) {
        const bf16x8 bb = *(const bf16x8*)&s_w[wn * 96 + 16 * f + l15][8 * lg4];
        o2[f] = __builtin_amdgcn_mfma_f32_16x16x32_bf16(a, bb, o2[f], 0, 0, 0);
      }
      __syncthreads();
    }
  }

  const float* b2p = f2b + depth * 192;
  const float* g2p = g2 + depth * 192;
#pragma unroll
  for (int f = 0; f < 6; ++f) {
    const int col = wn * 96 + 16 * f + l15;
#pragma unroll
    for (int reg = 0; reg < 4; ++reg)
      xb[((size_t)tok0 + rl + reg) * 192 + col] =
          xbn[f][reg] + (o2[f][reg] + b2p[col]) * g2p[col];
  }
}

// ---------------------------------------------------------------------------
// K4: feat = LN(mean_n xb); out = feat @ head_w + head_b.
// ---------------------------------------------------------------------------
__global__ __launch_bounds__(192) void k4_head(
    const float* __restrict__ xb, const float* __restrict__ flnw,
    const float* __restrict__ flnb, const float* __restrict__ hw,
    const float* __restrict__ hb, float* __restrict__ out) {
  const int b = blockIdx.x, t = threadIdx.x;
  const int w = t >> 6, lane = t & 63;
  float s = 0.f;
  const float* base = xb + (size_t)b * 256 * 192 + t;
#pragma unroll 4
  for (int n = 0; n < 256; ++n) s += base[n * 192];
  const float feat_pre = s * (1.f / 256.f);
  __shared__ float red[3];
  __shared__ float feat[192];
  float sm = wsum64(feat_pre);
  if (lane == 0) red[w] = sm;
  __syncthreads();
  const float mean = (red[0] + red[1] + red[2]) * (1.f / 192.f);
  __syncthreads();
  const float dd = feat_pre - mean;
  sm = wsum64(dd * dd);
  if (lane == 0) red[w] = sm;
  __syncthreads();
  const float var = (red[0] + red[1] + red[2]) * (1.f / 192.f);
  feat[t] = dd * rsqrtf(var + 1e-5f) * flnw[t] + flnb[t];
  __syncthreads();
  if (t < 9) {
    float a = hb[t];
    for (int d = 0; d < 192; ++d) a = fmaf(feat[d], hw[d * 9 + t], a);
    out[b * 9 + t] = a;
  }
}

// ---------------------------------------------------------------------------
extern "C" void kernel_launch(void* const* d_in, const int* in_sizes, int n_in,
                              void* d_out, int out_size, void* d_ws, size_t ws_size,
                              hipStream_t stream) {
  (void)in_sizes; (void)n_in; (void)out_size; (void)ws_size;
  const float* x          = (const float*)d_in[0];
  const float* band_w     = (const float*)d_in[1];
  const float* band_b     = (const float*)d_in[2];
  const float* dw_w       = (const float*)d_in[3];
  const float* pw_w       = (const float*)d_in[4];
  const float* pe_ln_w    = (const float*)d_in[5];
  const float* pe_ln_b    = (const float*)d_in[6];
  const float* spec_proto = (const float*)d_in[7];
  const float* spat_proto = (const float*)d_in[8];
  const float* r1_w       = (const float*)d_in[9];
  const float* r1_b       = (const float*)d_in[10];
  const float* r2_w       = (const float*)d_in[11];
  const float* r2_b       = (const float*)d_in[12];
  const float* key_w      = (const float*)d_in[13];
  const float* pos_bias   = (const float*)d_in[14];
  const float* blk_ln_w   = (const float*)d_in[15];
  const float* blk_ln_b   = (const float*)d_in[16];
  const float* blk_q_w    = (const float*)d_in[17];
  const float* blk_v_w    = (const float*)d_in[18];
  const float* blk_f1_w   = (const float*)d_in[19];
  const float* blk_f1_b   = (const float*)d_in[20];
  const float* blk_f2_w   = (const float*)d_in[21];
  const float* blk_f2_b   = (const float*)d_in[22];
  const float* blk_g1     = (const float*)d_in[23];
  const float* blk_g2     = (const float*)d_in[24];
  const float* fin_ln_w   = (const float*)d_in[25];
  const float* fin_ln_b   = (const float*)d_in[26];
  const float* head_w     = (const float*)d_in[27];
  const float* head_b     = (const float*)d_in[28];

  float* ws    = (float*)d_ws;
  float* dw    = ws;                   //    65,536 f32
  float* xbuf  = dw + 65536;           // 1,572,864 f32
  float* bandT = xbuf + 1572864;       //     1,024 f32 (824 used)
  ushort* ush    = (ushort*)(bandT + 1024);
  ushort* qs_bf  = ush;                // 1,572,864
  ushort* kvT    = qs_bf + 1572864;    // 1,179,648
  ushort* keysT  = kvT + 1179648;      // 1,572,864
  ushort* vT     = keysT + 1572864;    // 1,572,864
  ushort* qwT    = vT + 1572864;       //   110,592
  ushort* vwT    = qwT + 110592;       //   110,592
  ushort* f1T    = vwT + 110592;       //   221,184
  ushort* f2T    = f1T + 221184;       //   221,184
  ushort* r1T    = f2T + 221184;       //    24,576
  ushort* r2T    = r1T + 24576;        //     6,144
  ushort* keyT   = r2T + 6144;         //    43,008

  prep_w<<<864, 256, 0, stream>>>(blk_q_w, blk_v_w, blk_f1_w, blk_f2_w,
                                  r1_w, r2_w, key_w, band_w,
                                  qwT, vwT, f1T, f2T, r1T, r2T, keyT, bandT);
  k1_band_dw<<<512, 512, 0, stream>>>(x, bandT, band_b, dw_w, dw);
  k2_mfma<<<256, 256, 0, stream>>>(dw, pw_w, pe_ln_w, pe_ln_b, spec_proto,
                                   spat_proto, r1T, r1_b, r2T, r2_b, keyT,
                                   pos_bias, xbuf, keysT);
  for (int d = 0; d < 3; ++d) {
    k3a_mfma<<<256, 256, 0, stream>>>(xbuf, blk_ln_w, blk_ln_b, qwT, vwT,
                                      qs_bf, vT, d);
    k3b_mfma<<<192, 256, 0, stream>>>(vT, keysT, kvT);
    k3c_mfma<<<256, 256, 0, stream>>>(xbuf, qs_bf, kvT, blk_ln_w, blk_ln_b,
                                      f1T, f2T, blk_f1_b, blk_f2_b, blk_g1,
                                      blk_g2, d);
  }
  k4_head<<<32, 192, 0, stream>>>(xbuf, fin_ln_w, fin_ln_b, head_w, head_b,
                                  (float*)d_out);
}